// Round 11
// baseline (193.990 us; speedup 1.0000x reference)
//
#include <hip/hip_runtime.h>
#include <hip/hip_bf16.h>
#include <hip/hip_fp16.h>

#define NN 4096
#define FIN 512
#define FOUT 64
#define NH 8
#define ALPHA 0.2f
#define PSCALE 4096.0f   // 2^12 row-invariant P scale (C/Cd invariant)

typedef unsigned int uint;
typedef unsigned short ushort;
typedef unsigned char uchar;
typedef unsigned long long ull;
typedef __attribute__((ext_vector_type(8))) short short8;
typedef __attribute__((ext_vector_type(8))) _Float16 half8;
typedef __attribute__((ext_vector_type(4))) float floatx4;
typedef __attribute__((ext_vector_type(4))) uint uintx4;
typedef __attribute__((ext_vector_type(2))) uint uintx2;

__device__ __forceinline__ float bf2f(ushort s) { return __uint_as_float(((uint)s) << 16); }
__device__ __forceinline__ ushort f2bf(float f) {
    uint u = __float_as_uint(f);
    u += 0x7fffu + ((u >> 16) & 1u);   // RNE
    return (ushort)(u >> 16);
}
__device__ __forceinline__ ushort f2h(float f) {
    return __half_as_ushort(__float2half_rn(f));
}

// inline dtype probe: wave-uniform, deterministic (same 64 samples everywhere)
__device__ __forceinline__ int detect_bf16(const ushort* __restrict__ hraw) {
    int lane = threadIdx.x & 63;
    float a = fabsf(bf2f(hraw[2 * lane]));
    ull bal = __ballot(a >= 1e-3f && a <= 100.0f);
    return __popcll(bal) >= 32;
}

// ---------------------------------------------------------------------------
// Fused prep: [0,8192) packmask | [8192,9216) convert h (8 elem/thread) |
//             [9216,9248) transw   (unchanged from passing rounds)
// ---------------------------------------------------------------------------
#define PM_BLKS 8192
#define CV_BLKS 1024
#define TW_BLKS 32

__global__ __launch_bounds__(256) void prep_kernel(
    const int* __restrict__ mask, uchar* __restrict__ mb,
    const void* __restrict__ hraw, ushort* __restrict__ bh,
    const void* __restrict__ Wraw, ushort* __restrict__ WT)
{
    const int b = blockIdx.x, t = threadIdx.x;
    if (b < PM_BLKS) {
        size_t gid = (size_t)b * 256 + t;
        const int* p = mask + gid * 8;
        int4 aa = *(const int4*)p;
        int4 bb = *(const int4*)(p + 4);
        uint by = (uint)(aa.x > 0)        | ((uint)(aa.y > 0) << 1)
                | ((uint)(aa.z > 0) << 2) | ((uint)(aa.w > 0) << 3)
                | ((uint)(bb.x > 0) << 4) | ((uint)(bb.y > 0) << 5)
                | ((uint)(bb.z > 0) << 6) | ((uint)(bb.w > 0) << 7);
        mb[gid] = (uchar)by;
    } else if (b < PM_BLKS + CV_BLKS) {
        int isbf = detect_bf16((const ushort*)hraw);
        size_t e0 = ((size_t)(b - PM_BLKS) * 256 + t) * 8;
        if (isbf) {
            *(uint4*)(bh + e0) = *(const uint4*)((const ushort*)hraw + e0);
        } else {
            const float* s = (const float*)hraw + e0;
            float4 f0 = *(const float4*)s;
            float4 f1 = *(const float4*)(s + 4);
            uint4 o;
            o.x = (uint)f2bf(f0.x) | ((uint)f2bf(f0.y) << 16);
            o.y = (uint)f2bf(f0.z) | ((uint)f2bf(f0.w) << 16);
            o.z = (uint)f2bf(f1.x) | ((uint)f2bf(f1.y) << 16);
            o.w = (uint)f2bf(f1.z) | ((uint)f2bf(f1.w) << 16);
            *(uint4*)(bh + e0) = o;
        }
    } else {
        int isbf = detect_bf16((const ushort*)hraw);
        int b2 = b - PM_BLKS - CV_BLKS;
        int h = b2 >> 2, kq = b2 & 3;
        int o = t & 63, sub = t >> 6;
        int kbase = kq * 128 + sub * 32;
        uint pk[16];
#pragma unroll
        for (int kk = 0; kk < 32; kk += 2) {
            float v0, v1;
            size_t s0 = ((size_t)h * FIN + kbase + kk) * FOUT + o;
            size_t s1 = s0 + FOUT;
            if (isbf) { v0 = bf2f(((const ushort*)Wraw)[s0]); v1 = bf2f(((const ushort*)Wraw)[s1]); }
            else      { v0 = ((const float*)Wraw)[s0];        v1 = ((const float*)Wraw)[s1]; }
            pk[kk >> 1] = (uint)f2h(v0) | ((uint)f2h(v1) << 16);
        }
        ushort* dst = WT + ((size_t)h * FOUT + o) * FIN + kbase;
#pragma unroll
        for (int q = 0; q < 4; q++)
            *(uint4*)(dst + q * 8) = make_uint4(pk[q*4], pk[q*4+1], pk[q*4+2], pk[q*4+3]);
    }
}

// per-head tables (fp16): Kh = max_j er'; v_j = e^{er-Kh}; z_j = e^{alpha(er-Kh)}
__global__ __launch_bounds__(256) void khv_kernel(const float* __restrict__ er,
                                                  float* __restrict__ Kh,
                                                  ushort* __restrict__ vt,
                                                  ushort* __restrict__ zt) {
    __shared__ float red[256];
    int h = blockIdx.x >> 3, sl = blockIdx.x & 7, t = threadIdx.x;
    float m = -3.0e38f;
    for (int j = t; j < NN; j += 256) m = fmaxf(m, er[(size_t)h * NN + j]);
    red[t] = m;
    __syncthreads();
    for (int s = 128; s >= 1; s >>= 1) {
        if (t < s) red[t] = fmaxf(red[t], red[t + s]);
        __syncthreads();
    }
    float kh = red[0];
    if (t == 0 && sl == 0) Kh[h] = kh;
    int j = sl * 512 + t;
#pragma unroll
    for (int q = 0; q < 2; q++, j += 256) {
        float d = er[(size_t)h * NN + j] - kh;
        vt[(size_t)h * NN + j] = f2h(__expf(d));
        zt[(size_t)h * NN + j] = f2h(__expf(ALPHA * d));
    }
}

// ---------------------------------------------------------------------------
// Stage 1 (MFMA): Wh = h*W + bW; WhT[h][o][n] fp16; el/er dots (f32)
// NOTE: WT is now fp16 (prep converts with f2h) and the MFMA here is f16 —
// A (h) stays bf16->? A is bh (bf16)... mixed operands are NOT allowed, so
// wh keeps bf16 MFMA with bf16 WT. See below: prep still writes bf16 WT.
// ---------------------------------------------------------------------------
__global__ __launch_bounds__(256) void wh_kernel(
    const ushort* __restrict__ hmat, const ushort* __restrict__ WT,
    const void* __restrict__ bWr, const void* __restrict__ alr,
    const void* __restrict__ arr, const void* __restrict__ bAr,
    const ushort* __restrict__ hraw,
    ushort* __restrict__ WhT, float* __restrict__ el, float* __restrict__ er)
{
    __shared__ __align__(16) ushort sT[64][72];
    const int t = threadIdx.x, lane = t & 63, wid = t >> 6;
    const int head = blockIdx.y, rbase = blockIdx.x * 64;
    const int lm = lane & 15, lq = lane >> 4;

    floatx4 C[4];
#pragma unroll
    for (int cg = 0; cg < 4; cg++) C[cg] = (floatx4){0.f, 0.f, 0.f, 0.f};

    const ushort* Ap = hmat + (size_t)(rbase + wid * 16 + lm) * FIN + lq * 8;
    const ushort* Bp = WT + (size_t)head * FOUT * FIN + (size_t)lm * FIN + lq * 8;

#pragma unroll
    for (int kc = 0; kc < 16; kc++) {
        half8 a;
        {   // convert bf16 A fragment to fp16 on the fly (exact: bf16->f32->f16
            // is exact for bf16 values within f16 range; h ~ O(1))
            short8 ab = *(const short8*)(Ap + kc * 32);
            union { ushort u[8]; half8 h; } cv;
#pragma unroll
            for (int e = 0; e < 8; e++) cv.u[e] = f2h(bf2f(((ushort*)&ab)[e]));
            a = cv.h;
        }
#pragma unroll
        for (int cg = 0; cg < 4; cg++) {
            half8 bfr = *(const half8*)(Bp + (size_t)cg * 16 * FIN + kc * 32);
            C[cg] = __builtin_amdgcn_mfma_f32_16x16x32_f16(a, bfr, C[cg], 0, 0, 0);
        }
    }

    const int isbf = detect_bf16(hraw);
    float bA = isbf ? bf2f(((const ushort*)bAr)[head]) : ((const float*)bAr)[head];
    float pel[4] = {0.f, 0.f, 0.f, 0.f}, per[4] = {0.f, 0.f, 0.f, 0.f};
#pragma unroll
    for (int cg = 0; cg < 4; cg++) {
        int o = head * FOUT + cg * 16 + lm;
        float bw = isbf ? bf2f(((const ushort*)bWr)[o]) : ((const float*)bWr)[o];
        float av = isbf ? bf2f(((const ushort*)alr)[o]) : ((const float*)alr)[o];
        float rv = isbf ? bf2f(((const ushort*)arr)[o]) : ((const float*)arr)[o];
        ushort pk[4];
#pragma unroll
        for (int r = 0; r < 4; r++) {
            float v = C[cg][r] + bw;
            pel[r] += v * av;
            per[r] += v * rv;
            pk[r] = f2h(v);                    // fp16 WhT for stage 2
        }
        ushort4 p4; p4.x = pk[0]; p4.y = pk[1]; p4.z = pk[2]; p4.w = pk[3];
        *(ushort4*)(&sT[cg * 16 + lm][wid * 16 + lq * 4]) = p4;
    }
#pragma unroll
    for (int off = 1; off < 16; off <<= 1) {
#pragma unroll
        for (int r = 0; r < 4; r++) {
            pel[r] += __shfl_xor(pel[r], off);
            per[r] += __shfl_xor(per[r], off);
        }
    }
    if (lm == 0) {
#pragma unroll
        for (int r = 0; r < 4; r++) {
            int row = rbase + wid * 16 + lq * 4 + r;
            el[(size_t)head * NN + row] = pel[r];
            er[(size_t)head * NN + row] = per[r] + bA;
        }
    }
    __syncthreads();
    {
        int o = t >> 2, ch = t & 3;
        uint4 v0 = *(const uint4*)(&sT[o][ch * 16]);
        uint4 v1 = *(const uint4*)(&sT[o][ch * 16 + 8]);
        ushort* d = WhT + ((size_t)head * FOUT + o) * NN + rbase + ch * 16;
        *(uint4*)d = v0;
        *(uint4*)(d + 8) = v1;
    }
}

// ---------------------------------------------------------------------------
// Stage 2 (R24 = R23 + quarter-split): pay the per-phase fixed cost 16x
// instead of 32x. 512 thr = 8 waves = 2 row-groups x 4 j-quarters; each wave
// 32 i-rows x 1024 j = 16 tiles. LDS 73.7KB -> 2 blocks/CU -> 16 waves/CU
// (4/SIMD, double R23). Per-phase schedule byte-identical to R23 (lwrite,
// gload, VZLOAD, compute, counted BARRIER). 4-way merge at the end.
// ---------------------------------------------------------------------------
__device__ __forceinline__ uint pkmul(uint a, uint b) {
    uint d; asm("v_pk_mul_f16 %0,%1,%2" : "=v"(d) : "v"(a), "v"(b)); return d;
}
__device__ __forceinline__ uint pkmax(uint a, uint b) {
    uint d; asm("v_pk_max_f16 %0,%1,%2" : "=v"(d) : "v"(a), "v"(b)); return d;
}
// bits 0,1 of a -> 0x0000FFFF / 0xFFFF0000 select words
__device__ __forceinline__ uint pmask2(uint a) {
    uint b = a & 3u;
    return ((b | (b << 15)) & 0x10001u) * 0xFFFFu;
}
__device__ __forceinline__ half8 pgen8h(uintx4 vv, uintx4 zz, uint mby,
                                        uint uip, uint wip) {
    union { uintx4 u; half8 h; } c;
    c.u.x = pkmax(pkmul(uip, vv.x), pkmul(wip, zz.x)) & pmask2(mby);
    c.u.y = pkmax(pkmul(uip, vv.y), pkmul(wip, zz.y)) & pmask2(mby >> 2);
    c.u.z = pkmax(pkmul(uip, vv.z), pkmul(wip, zz.z)) & pmask2(mby >> 4);
    c.u.w = pkmax(pkmul(uip, vv.w), pkmul(wip, zz.w)) & pmask2(mby >> 6);
    return c.h;
}

#define KEEP(x) asm volatile("" : "+v"(x))
// counted barrier: LDS-write visibility only; vmcnt stays counted at use sites
#define BARRIER() do { asm volatile("s_waitcnt lgkmcnt(0)" ::: "memory"); \
                       __builtin_amdgcn_s_barrier(); } while (0)

#define VZLOAD(S, j0) do {                                   \
    v##S##a = *(const uintx4*)(gvt + (j0) + sh8);            \
    v##S##b = *(const uintx4*)(gvt + (j0) + 32 + sh8);       \
    z##S##a = *(const uintx4*)(gzt + (j0) + sh8);            \
    z##S##b = *(const uintx4*)(gzt + (j0) + 32 + sh8);       \
} while (0)

__global__ __launch_bounds__(512, 4) void attn_kernel(
    const uchar* __restrict__ mb,      // [NN][512] bitmask
    const ushort* __restrict__ WhT,    // [H][FOUT][NN] fp16
    const float* __restrict__ el, const float* __restrict__ Kh,
    const ushort* __restrict__ vt, const ushort* __restrict__ zt,
    const ushort* __restrict__ hraw,
    void* __restrict__ outv)
{
    __shared__ __align__(16) ushort sB[4][2][64 * 72];  // [jq][dbuf] tiles

    const int t = threadIdx.x, lane = t & 63, wid = t >> 6;  // 8 waves
    const int rg = wid >> 2;       // row group (32 rows each)
    const int jq = wid & 3;        // j quarter (1024 j each)
    const int b = blockIdx.x;
    const int head = b & 7;                       // XCD swizzle
    const int ibase = (b >> 3) * 64;
    const int lm = lane & 15, lq = lane >> 4;
    const int sh8 = lq * 8;

    // per-lane row constants for rows lm and lm+16 of this wave's 32 rows
    const float kh = Kh[head];
    const int rowa = ibase + rg * 32 + lm;
    const float xa = el[(size_t)head * NN + rowa] + kh;
    const float xb = el[(size_t)head * NN + rowa + 16] + kh;
    const float Ma = fmaxf(xa, ALPHA * xa);
    const float Mb = fmaxf(xb, ALPHA * xb);
    const uint uipa = (uint)f2h(PSCALE * __expf(xa - Ma)) * 0x10001u;
    const uint wipa = (uint)f2h(PSCALE * __expf(ALPHA * xa - Ma)) * 0x10001u;
    const uint uipb = (uint)f2h(PSCALE * __expf(xb - Mb)) * 0x10001u;
    const uint wipb = (uint)f2h(PSCALE * __expf(ALPHA * xb - Mb)) * 0x10001u;

    // staging: the 128 threads of each j-quarter (waves rg0/jq and rg1/jq)
    // stage that quarter's tile. st in [0,128): so = B row, sc = 64B col grp.
    const int jb = jq * 1024;
    const int st = rg * 64 + lane;
    const int so = st >> 1;
    const int sc = (st & 1) * 32;
    const ushort* gB = WhT + ((size_t)head * FOUT + so) * NN + jb + sc;
    const ushort* gvt = vt + (size_t)head * NN + jb;
    const ushort* gzt = zt + (size_t)head * NN + jb;
    const uchar* mra = mb + (size_t)rowa * 512 + (jb >> 3);
    const uchar* mrb = mra + 16 * 512;

    uintx4 rr0, rr1, rr2, rr3;
    uintx2 mka_s, mkb_s;

    auto gload = [&](int j0) {     // j0 local to this quarter, in [0,1024)
        rr0 = *(const uintx4*)(gB + j0);
        rr1 = *(const uintx4*)(gB + j0 + 8);
        rr2 = *(const uintx4*)(gB + j0 + 16);
        rr3 = *(const uintx4*)(gB + j0 + 24);
        mka_s = *(const uintx2*)(mra + (j0 >> 3));
        mkb_s = *(const uintx2*)(mrb + (j0 >> 3));
    };
    auto lwrite = [&](int buf) {
        ushort* d = &sB[jq][buf][so * 72 + sc];
        *(uintx4*)(d)      = rr0;
        *(uintx4*)(d + 8)  = rr1;
        *(uintx4*)(d + 16) = rr2;
        *(uintx4*)(d + 24) = rr3;
    };

    uintx4 v0a, v0b, z0a, z0b;
    uintx4 v1a, v1b, z1a, z1b;

    const half8 onesh = {(_Float16)1.f, (_Float16)1.f, (_Float16)1.f, (_Float16)1.f,
                         (_Float16)1.f, (_Float16)1.f, (_Float16)1.f, (_Float16)1.f};
    floatx4 Z = {0.f, 0.f, 0.f, 0.f};
    floatx4 C0 = Z, C1 = Z, C2 = Z, C3 = Z, Cd0 = Z;
    floatx4 C4 = Z, C5 = Z, C6 = Z, C7 = Z, Cd1 = Z;

    auto compute = [&](int buf, uintx2 mka, uintx2 mkb,
                       uintx4 vA, uintx4 vB, uintx4 zA, uintx4 zB) {
        uint m0a = mka.x >> sh8;
        uint m1a = mka.y >> sh8;
        uint m0b = mkb.x >> sh8;
        uint m1b = mkb.y >> sh8;
        half8 a0 = pgen8h(vA, zA, m0a, uipa, wipa);   // rows lm,    j 0..31
        half8 a1 = pgen8h(vB, zB, m1a, uipa, wipa);   // rows lm,    j 32..63
        half8 a2 = pgen8h(vA, zA, m0b, uipb, wipb);   // rows lm+16, j 0..31
        half8 a3 = pgen8h(vB, zB, m1b, uipb, wipb);   // rows lm+16, j 32..63
        const ushort* base = &sB[jq][buf][0];
        half8 b00 = *(const half8*)(base + (0  + lm) * 72 + sh8);
        half8 b10 = *(const half8*)(base + (16 + lm) * 72 + sh8);
        half8 b20 = *(const half8*)(base + (32 + lm) * 72 + sh8);
        half8 b30 = *(const half8*)(base + (48 + lm) * 72 + sh8);
        Cd0 = __builtin_amdgcn_mfma_f32_16x16x32_f16(a0, onesh, Cd0, 0, 0, 0);
        Cd1 = __builtin_amdgcn_mfma_f32_16x16x32_f16(a2, onesh, Cd1, 0, 0, 0);
        C0 = __builtin_amdgcn_mfma_f32_16x16x32_f16(a0, b00, C0, 0, 0, 0);
        C4 = __builtin_amdgcn_mfma_f32_16x16x32_f16(a2, b00, C4, 0, 0, 0);
        C1 = __builtin_amdgcn_mfma_f32_16x16x32_f16(a0, b10, C1, 0, 0, 0);
        C5 = __builtin_amdgcn_mfma_f32_16x16x32_f16(a2, b10, C5, 0, 0, 0);
        C2 = __builtin_amdgcn_mfma_f32_16x16x32_f16(a0, b20, C2, 0, 0, 0);
        C6 = __builtin_amdgcn_mfma_f32_16x16x32_f16(a2, b20, C6, 0, 0, 0);
        C3 = __builtin_amdgcn_mfma_f32_16x16x32_f16(a0, b30, C3, 0, 0, 0);
        C7 = __builtin_amdgcn_mfma_f32_16x16x32_f16(a2, b30, C7, 0, 0, 0);
        half8 b01 = *(const half8*)(base + (0  + lm) * 72 + 32 + sh8);
        half8 b11 = *(const half8*)(base + (16 + lm) * 72 + 32 + sh8);
        half8 b21 = *(const half8*)(base + (32 + lm) * 72 + 32 + sh8);
        half8 b31 = *(const half8*)(base + (48 + lm) * 72 + 32 + sh8);
        Cd0 = __builtin_amdgcn_mfma_f32_16x16x32_f16(a1, onesh, Cd0, 0, 0, 0);
        Cd1 = __builtin_amdgcn_mfma_f32_16x16x32_f16(a3, onesh, Cd1, 0, 0, 0);
        C0 = __builtin_amdgcn_mfma_f32_16x16x32_f16(a1, b01, C0, 0, 0, 0);
        C4 = __builtin_amdgcn_mfma_f32_16x16x32_f16(a3, b01, C4, 0, 0, 0);
        C1 = __builtin_amdgcn_mfma_f32_16x16x32_f16(a1, b11, C1, 0, 0, 0);
        C5 = __builtin_amdgcn_mfma_f32_16x16x32_f16(a3, b11, C5, 0, 0, 0);
        C2 = __builtin_amdgcn_mfma_f32_16x16x32_f16(a1, b21, C2, 0, 0, 0);
        C6 = __builtin_amdgcn_mfma_f32_16x16x32_f16(a3, b21, C6, 0, 0, 0);
        C3 = __builtin_amdgcn_mfma_f32_16x16x32_f16(a1, b31, C3, 0, 0, 0);
        C7 = __builtin_amdgcn_mfma_f32_16x16x32_f16(a3, b31, C7, 0, 0, 0);
    };

    // prologue: buf0 <- tile 0 of this quarter; rr <- tile 1; vz0 <- tile 0
    uintx2 mka0, mkb0, mka1, mkb1;
    gload(0);
    lwrite(0);
    mka0 = mka_s; mkb0 = mkb_s;
    gload(64);
    VZLOAD(0, 0);
    KEEP(rr0); KEEP(rr1); KEEP(rr2); KEEP(rr3);
    KEEP(v0a); KEEP(v0b); KEEP(z0a); KEEP(z0b);
    BARRIER();

    // main loop: 16 tiles per wave, 1 counted barrier per tile; prefetch
    // issued before compute and pinned live; loads cross the barrier.
    for (int it = 0; it < 16; it += 2) {
        // phase A: compute tile it (buf0, vz0)
        lwrite(1);                               // tile it+1 -> buf1
        mka1 = mka_s; mkb1 = mkb_s;
        gload(((it + 2) & 15) * 64);             // rr <- tile it+2
        VZLOAD(1, (it + 1) * 64);                // vz1 <- tile it+1
        compute(0, mka0, mkb0, v0a, v0b, z0a, z0b);
        KEEP(v1a); KEEP(v1b); KEEP(z1a); KEEP(z1b);
        KEEP(rr0); KEEP(rr1); KEEP(rr2); KEEP(rr3);
        BARRIER();
        // phase B: compute tile it+1 (buf1, vz1)
        lwrite(0);                               // tile it+2 -> buf0
        mka0 = mka_s; mkb0 = mkb_s;
        gload(((it + 3) & 15) * 64);             // rr <- tile it+3
        VZLOAD(0, ((it + 2) & 15) * 64);         // vz0 <- tile it+2
        compute(1, mka1, mkb1, v1a, v1b, z1a, z1b);
        KEEP(v0a); KEEP(v0b); KEEP(z0a); KEEP(z0b);
        KEEP(rr0); KEEP(rr1); KEEP(rr2); KEEP(rr3);
        BARRIER();
    }

    // merge j-quarters: jq=1..3 publish partials via LDS, jq=0 accumulates.
    // lane stride 44 dwords (16B-aligned); 3 x 128 x 44 x 4B = 67.6KB <= 73.7KB
    float* mg = (float*)&sB[0][0][0];
    const int mi = ((jq - 1) * 128 + rg * 64 + lane) * 44;
    if (jq > 0) {
        float* p = &mg[mi];
        *(floatx4*)(p + 0)  = C0;  *(floatx4*)(p + 4)  = C1;
        *(floatx4*)(p + 8)  = C2;  *(floatx4*)(p + 12) = C3;
        *(floatx4*)(p + 16) = C4;  *(floatx4*)(p + 20) = C5;
        *(floatx4*)(p + 24) = C6;  *(floatx4*)(p + 28) = C7;
        *(floatx4*)(p + 32) = Cd0; *(floatx4*)(p + 36) = Cd1;
    }
    BARRIER();
    if (jq == 0) {
#pragma unroll
        for (int s = 0; s < 3; s++) {
            const float* p = &mg[(s * 128 + rg * 64 + lane) * 44];
            C0 += *(const floatx4*)(p + 0);   C1 += *(const floatx4*)(p + 4);
            C2 += *(const floatx4*)(p + 8);   C3 += *(const floatx4*)(p + 12);
            C4 += *(const floatx4*)(p + 16);  C5 += *(const floatx4*)(p + 20);
            C6 += *(const floatx4*)(p + 24);  C7 += *(const floatx4*)(p + 28);
            Cd0 += *(const floatx4*)(p + 32); Cd1 += *(const floatx4*)(p + 36);
        }
        // epilogue: normalize, elu, store (two row groups per lane)
        const int isbf = detect_bf16(hraw);
#pragma unroll
        for (int r = 0; r < 4; r++) {
            int ra = ibase + rg * 32 + lq * 4 + r;
            int rb = ra + 16;
            float inva = 1.f / Cd0[r];
            float invb = 1.f / Cd1[r];
            float x0 = C0[r] * inva; x0 = (x0 > 0.f) ? x0 : __expf(x0) - 1.f;
            float x1 = C1[r] * inva; x1 = (x1 > 0.f) ? x1 : __expf(x1) - 1.f;
            float x2 = C2[r] * inva; x2 = (x2 > 0.f) ? x2 : __expf(x2) - 1.f;
            float x3 = C3[r] * inva; x3 = (x3 > 0.f) ? x3 : __expf(x3) - 1.f;
            float y0 = C4[r] * invb; y0 = (y0 > 0.f) ? y0 : __expf(y0) - 1.f;
            float y1 = C5[r] * invb; y1 = (y1 > 0.f) ? y1 : __expf(y1) - 1.f;
            float y2 = C6[r] * invb; y2 = (y2 > 0.f) ? y2 : __expf(y2) - 1.f;
            float y3 = C7[r] * invb; y3 = (y3 > 0.f) ? y3 : __expf(y3) - 1.f;
            size_t basea = (size_t)ra * (NH * FOUT) + head * FOUT + lm;
            size_t baseb = (size_t)rb * (NH * FOUT) + head * FOUT + lm;
            if (isbf) {
                ushort* o = (ushort*)outv;
                o[basea + 0]  = f2bf(x0);
                o[basea + 16] = f2bf(x1);
                o[basea + 32] = f2bf(x2);
                o[basea + 48] = f2bf(x3);
                o[baseb + 0]  = f2bf(y0);
                o[baseb + 16] = f2bf(y1);
                o[baseb + 32] = f2bf(y2);
                o[baseb + 48] = f2bf(y3);
            } else {
                float* o = (float*)outv;
                o[basea + 0]  = x0;
                o[basea + 16] = x1;
                o[basea + 32] = x2;
                o[basea + 48] = x3;
                o[baseb + 0]  = y0;
                o[baseb + 16] = y1;
                o[baseb + 32] = y2;
                o[baseb + 48] = y3;
            }
        }
    }
}

extern "C" void kernel_launch(void* const* d_in, const int* in_sizes, int n_in,
                              void* d_out, int out_size, void* d_ws, size_t ws_size,
                              hipStream_t stream)
{
    const void* hraw = d_in[0];
    const int*  mask = (const int*)d_in[1];
    const void* Wraw = d_in[2];
    const void* bWr  = d_in[3];
    const void* alr  = d_in[4];
    const void* arr  = d_in[5];
    const void* bAr  = d_in[6];

    char* w = (char*)d_ws;
    ushort* bh   = (ushort*)w;                  w += (size_t)NN * FIN * 2;        // 4 MB
    ushort* WT   = (ushort*)w;                  w += (size_t)NH * FOUT * FIN * 2; // 512 KB
    ushort* WhT  = (ushort*)w;                  w += (size_t)NH * FOUT * NN * 2;  // 4 MB
    float*  el   = (float*)w;                   w += (size_t)NH * NN * 4;
    float*  er   = (float*)w;                   w += (size_t)NH * NN * 4;
    float*  Kh   = (float*)w;                   w += 64;
    ushort* vt   = (ushort*)w;                  w += (size_t)NH * NN * 4;  // fp16, slack kept
    ushort* zt   = (ushort*)w;                  w += (size_t)NH * NN * 4;
    uchar*  mb   = (uchar*)w;                   w += (size_t)NN * 512;            // 2 MB

    prep_kernel<<<PM_BLKS + CV_BLKS + TW_BLKS, 256, 0, stream>>>(
        mask, mb, hraw, bh, Wraw, WT);
    wh_kernel<<<dim3(NN / 64, NH), 256, 0, stream>>>(bh, WT, bWr, alr, arr, bAr,
                                                     (const ushort*)hraw, WhT, el, er);
    khv_kernel<<<64, 256, 0, stream>>>(er, Kh, vt, zt);
    attn_kernel<<<NN / 64 * NH, 512, 0, stream>>>(mb, WhT, el, Kh, vt, zt,
                                                  (const ushort*)hraw, d_out);
}

// Round 13
// 193.207 us; speedup vs baseline: 1.0041x; 1.0041x over previous
//
#include <hip/hip_runtime.h>
#include <hip/hip_bf16.h>
#include <hip/hip_fp16.h>

#define NN 4096
#define FIN 512
#define FOUT 64
#define NH 8
#define ALPHA 0.2f
#define PSCALE 4096.0f   // 2^12 row-invariant P scale (C/Cd invariant)

typedef unsigned int uint;
typedef unsigned short ushort;
typedef unsigned char uchar;
typedef unsigned long long ull;
typedef __attribute__((ext_vector_type(8))) short short8;
typedef __attribute__((ext_vector_type(8))) _Float16 half8;
typedef __attribute__((ext_vector_type(4))) float floatx4;
typedef __attribute__((ext_vector_type(4))) uint uintx4;
typedef __attribute__((ext_vector_type(2))) uint uintx2;

__device__ __forceinline__ float bf2f(ushort s) { return __uint_as_float(((uint)s) << 16); }
__device__ __forceinline__ ushort f2bf(float f) {
    uint u = __float_as_uint(f);
    u += 0x7fffu + ((u >> 16) & 1u);   // RNE
    return (ushort)(u >> 16);
}
__device__ __forceinline__ ushort f2h(float f) {
    return __half_as_ushort(__float2half_rn(f));
}

// inline dtype probe: wave-uniform, deterministic (same 64 samples everywhere)
__device__ __forceinline__ int detect_bf16(const ushort* __restrict__ hraw) {
    int lane = threadIdx.x & 63;
    float a = fabsf(bf2f(hraw[2 * lane]));
    ull bal = __ballot(a >= 1e-3f && a <= 100.0f);
    return __popcll(bal) >= 32;
}

// ---------------------------------------------------------------------------
// Fused prep: [0,8192) packmask | [8192,9216) convert h (8 elem/thread) |
//             [9216,9248) transw   (R23 version: bf16 WT)
// ---------------------------------------------------------------------------
#define PM_BLKS 8192
#define CV_BLKS 1024
#define TW_BLKS 32

__global__ __launch_bounds__(256) void prep_kernel(
    const int* __restrict__ mask, uchar* __restrict__ mb,
    const void* __restrict__ hraw, ushort* __restrict__ bh,
    const void* __restrict__ Wraw, ushort* __restrict__ WT)
{
    const int b = blockIdx.x, t = threadIdx.x;
    if (b < PM_BLKS) {
        size_t gid = (size_t)b * 256 + t;
        const int* p = mask + gid * 8;
        int4 aa = *(const int4*)p;
        int4 bb = *(const int4*)(p + 4);
        uint by = (uint)(aa.x > 0)        | ((uint)(aa.y > 0) << 1)
                | ((uint)(aa.z > 0) << 2) | ((uint)(aa.w > 0) << 3)
                | ((uint)(bb.x > 0) << 4) | ((uint)(bb.y > 0) << 5)
                | ((uint)(bb.z > 0) << 6) | ((uint)(bb.w > 0) << 7);
        mb[gid] = (uchar)by;
    } else if (b < PM_BLKS + CV_BLKS) {
        int isbf = detect_bf16((const ushort*)hraw);
        size_t e0 = ((size_t)(b - PM_BLKS) * 256 + t) * 8;
        if (isbf) {
            *(uint4*)(bh + e0) = *(const uint4*)((const ushort*)hraw + e0);
        } else {
            const float* s = (const float*)hraw + e0;
            float4 f0 = *(const float4*)s;
            float4 f1 = *(const float4*)(s + 4);
            uint4 o;
            o.x = (uint)f2bf(f0.x) | ((uint)f2bf(f0.y) << 16);
            o.y = (uint)f2bf(f0.z) | ((uint)f2bf(f0.w) << 16);
            o.z = (uint)f2bf(f1.x) | ((uint)f2bf(f1.y) << 16);
            o.w = (uint)f2bf(f1.z) | ((uint)f2bf(f1.w) << 16);
            *(uint4*)(bh + e0) = o;
        }
    } else {
        int isbf = detect_bf16((const ushort*)hraw);
        int b2 = b - PM_BLKS - CV_BLKS;
        int h = b2 >> 2, kq = b2 & 3;
        int o = t & 63, sub = t >> 6;
        int kbase = kq * 128 + sub * 32;
        uint pk[16];
#pragma unroll
        for (int kk = 0; kk < 32; kk += 2) {
            float v0, v1;
            size_t s0 = ((size_t)h * FIN + kbase + kk) * FOUT + o;
            size_t s1 = s0 + FOUT;
            if (isbf) { v0 = bf2f(((const ushort*)Wraw)[s0]); v1 = bf2f(((const ushort*)Wraw)[s1]); }
            else      { v0 = ((const float*)Wraw)[s0];        v1 = ((const float*)Wraw)[s1]; }
            pk[kk >> 1] = (uint)f2bf(v0) | ((uint)f2bf(v1) << 16);
        }
        ushort* dst = WT + ((size_t)h * FOUT + o) * FIN + kbase;
#pragma unroll
        for (int q = 0; q < 4; q++)
            *(uint4*)(dst + q * 8) = make_uint4(pk[q*4], pk[q*4+1], pk[q*4+2], pk[q*4+3]);
    }
}

// per-head tables (fp16): Kh = max_j er'; v_j = e^{er-Kh}; z_j = e^{alpha(er-Kh)}
__global__ __launch_bounds__(256) void khv_kernel(const float* __restrict__ er,
                                                  float* __restrict__ Kh,
                                                  ushort* __restrict__ vt,
                                                  ushort* __restrict__ zt) {
    __shared__ float red[256];
    int h = blockIdx.x >> 3, sl = blockIdx.x & 7, t = threadIdx.x;
    float m = -3.0e38f;
    for (int j = t; j < NN; j += 256) m = fmaxf(m, er[(size_t)h * NN + j]);
    red[t] = m;
    __syncthreads();
    for (int s = 128; s >= 1; s >>= 1) {
        if (t < s) red[t] = fmaxf(red[t], red[t + s]);
        __syncthreads();
    }
    float kh = red[0];
    if (t == 0 && sl == 0) Kh[h] = kh;
    int j = sl * 512 + t;
#pragma unroll
    for (int q = 0; q < 2; q++, j += 256) {
        float d = er[(size_t)h * NN + j] - kh;
        vt[(size_t)h * NN + j] = f2h(__expf(d));
        zt[(size_t)h * NN + j] = f2h(__expf(ALPHA * d));
    }
}

// ---------------------------------------------------------------------------
// Stage 1 (MFMA): Wh = h*W + bW; WhT[h][o][n] fp16; el/er dots (f32).
// R23 version: bf16 A, bf16 WT, bf16 MFMA (fast path); only WhT output fp16.
// ---------------------------------------------------------------------------
__global__ __launch_bounds__(256) void wh_kernel(
    const ushort* __restrict__ hmat, const ushort* __restrict__ WT,
    const void* __restrict__ bWr, const void* __restrict__ alr,
    const void* __restrict__ arr, const void* __restrict__ bAr,
    const ushort* __restrict__ hraw,
    ushort* __restrict__ WhT, float* __restrict__ el, float* __restrict__ er)
{
    __shared__ __align__(16) ushort sT[64][72];
    const int t = threadIdx.x, lane = t & 63, wid = t >> 6;
    const int head = blockIdx.y, rbase = blockIdx.x * 64;
    const int lm = lane & 15, lq = lane >> 4;

    floatx4 C[4];
#pragma unroll
    for (int cg = 0; cg < 4; cg++) C[cg] = (floatx4){0.f, 0.f, 0.f, 0.f};

    const ushort* Ap = hmat + (size_t)(rbase + wid * 16 + lm) * FIN + lq * 8;
    const ushort* Bp = WT + (size_t)head * FOUT * FIN + (size_t)lm * FIN + lq * 8;

#pragma unroll
    for (int kc = 0; kc < 16; kc++) {
        short8 a = *(const short8*)(Ap + kc * 32);
#pragma unroll
        for (int cg = 0; cg < 4; cg++) {
            short8 b = *(const short8*)(Bp + (size_t)cg * 16 * FIN + kc * 32);
            C[cg] = __builtin_amdgcn_mfma_f32_16x16x32_bf16(a, b, C[cg], 0, 0, 0);
        }
    }

    const int isbf = detect_bf16(hraw);
    float bA = isbf ? bf2f(((const ushort*)bAr)[head]) : ((const float*)bAr)[head];
    float pel[4] = {0.f, 0.f, 0.f, 0.f}, per[4] = {0.f, 0.f, 0.f, 0.f};
#pragma unroll
    for (int cg = 0; cg < 4; cg++) {
        int o = head * FOUT + cg * 16 + lm;
        float bw = isbf ? bf2f(((const ushort*)bWr)[o]) : ((const float*)bWr)[o];
        float av = isbf ? bf2f(((const ushort*)alr)[o]) : ((const float*)alr)[o];
        float rv = isbf ? bf2f(((const ushort*)arr)[o]) : ((const float*)arr)[o];
        ushort pk[4];
#pragma unroll
        for (int r = 0; r < 4; r++) {
            float v = C[cg][r] + bw;
            pel[r] += v * av;
            per[r] += v * rv;
            pk[r] = f2h(v);                    // fp16 WhT for stage 2
        }
        ushort4 p4; p4.x = pk[0]; p4.y = pk[1]; p4.z = pk[2]; p4.w = pk[3];
        *(ushort4*)(&sT[cg * 16 + lm][wid * 16 + lq * 4]) = p4;
    }
#pragma unroll
    for (int off = 1; off < 16; off <<= 1) {
#pragma unroll
        for (int r = 0; r < 4; r++) {
            pel[r] += __shfl_xor(pel[r], off);
            per[r] += __shfl_xor(per[r], off);
        }
    }
    if (lm == 0) {
#pragma unroll
        for (int r = 0; r < 4; r++) {
            int row = rbase + wid * 16 + lq * 4 + r;
            el[(size_t)head * NN + row] = pel[r];
            er[(size_t)head * NN + row] = per[r] + bA;
        }
    }
    __syncthreads();
    {
        int o = t >> 2, ch = t & 3;
        uint4 v0 = *(const uint4*)(&sT[o][ch * 16]);
        uint4 v1 = *(const uint4*)(&sT[o][ch * 16 + 8]);
        ushort* d = WhT + ((size_t)head * FOUT + o) * NN + rbase + ch * 16;
        *(uint4*)d = v0;
        *(uint4*)(d + 8) = v1;
    }
}

// ---------------------------------------------------------------------------
// Stage 2 (R26 = R25 resubmit): R24's quarter-split regressed ONLY because
// __launch_bounds__(512,4) forced 64 VGPR and spilled (~13MB scratch in
// WRITE_SIZE). Occupancy is LDS-capped at 2 blocks/CU = 4 waves/SIMD anyway,
// so declare (512,2) (VGPR cap 256) and let the ~120-reg live set fit.
// Structure unchanged: 8 waves = 2 row-groups x 4 j-quarters, 16 tiles/wave,
// counted barriers (R23-proven), fp16 packed P-gen (R21-proven).
// ---------------------------------------------------------------------------
__device__ __forceinline__ uint pkmul(uint a, uint b) {
    uint d; asm("v_pk_mul_f16 %0,%1,%2" : "=v"(d) : "v"(a), "v"(b)); return d;
}
__device__ __forceinline__ uint pkmax(uint a, uint b) {
    uint d; asm("v_pk_max_f16 %0,%1,%2" : "=v"(d) : "v"(a), "v"(b)); return d;
}
// bits 0,1 of a -> 0x0000FFFF / 0xFFFF0000 select words
__device__ __forceinline__ uint pmask2(uint a) {
    uint b = a & 3u;
    return ((b | (b << 15)) & 0x10001u) * 0xFFFFu;
}
__device__ __forceinline__ half8 pgen8h(uintx4 vv, uintx4 zz, uint mby,
                                        uint uip, uint wip) {
    union { uintx4 u; half8 h; } c;
    c.u.x = pkmax(pkmul(uip, vv.x), pkmul(wip, zz.x)) & pmask2(mby);
    c.u.y = pkmax(pkmul(uip, vv.y), pkmul(wip, zz.y)) & pmask2(mby >> 2);
    c.u.z = pkmax(pkmul(uip, vv.z), pkmul(wip, zz.z)) & pmask2(mby >> 4);
    c.u.w = pkmax(pkmul(uip, vv.w), pkmul(wip, zz.w)) & pmask2(mby >> 6);
    return c.h;
}

#define KEEP(x) asm volatile("" : "+v"(x))
// counted barrier: LDS-write visibility only; vmcnt stays counted at use sites
#define BARRIER() do { asm volatile("s_waitcnt lgkmcnt(0)" ::: "memory"); \
                       __builtin_amdgcn_s_barrier(); } while (0)

#define VZLOAD(S, j0) do {                                   \
    v##S##a = *(const uintx4*)(gvt + (j0) + sh8);            \
    v##S##b = *(const uintx4*)(gvt + (j0) + 32 + sh8);       \
    z##S##a = *(const uintx4*)(gzt + (j0) + sh8);            \
    z##S##b = *(const uintx4*)(gzt + (j0) + 32 + sh8);       \
} while (0)

__global__ __launch_bounds__(512, 2) void attn_kernel(
    const uchar* __restrict__ mb,      // [NN][512] bitmask
    const ushort* __restrict__ WhT,    // [H][FOUT][NN] fp16
    const float* __restrict__ el, const float* __restrict__ Kh,
    const ushort* __restrict__ vt, const ushort* __restrict__ zt,
    const ushort* __restrict__ hraw,
    void* __restrict__ outv)
{
    __shared__ __align__(16) ushort sB[4][2][64 * 72];  // [jq][dbuf] tiles

    const int t = threadIdx.x, lane = t & 63, wid = t >> 6;  // 8 waves
    const int rg = wid >> 2;       // row group (32 rows each)
    const int jq = wid & 3;        // j quarter (1024 j each)
    const int b = blockIdx.x;
    const int head = b & 7;                       // XCD swizzle
    const int ibase = (b >> 3) * 64;
    const int lm = lane & 15, lq = lane >> 4;
    const int sh8 = lq * 8;

    // per-lane row constants for rows lm and lm+16 of this wave's 32 rows
    const float kh = Kh[head];
    const int rowa = ibase + rg * 32 + lm;
    const float xa = el[(size_t)head * NN + rowa] + kh;
    const float xb = el[(size_t)head * NN + rowa + 16] + kh;
    const float Ma = fmaxf(xa, ALPHA * xa);
    const float Mb = fmaxf(xb, ALPHA * xb);
    const uint uipa = (uint)f2h(PSCALE * __expf(xa - Ma)) * 0x10001u;
    const uint wipa = (uint)f2h(PSCALE * __expf(ALPHA * xa - Ma)) * 0x10001u;
    const uint uipb = (uint)f2h(PSCALE * __expf(xb - Mb)) * 0x10001u;
    const uint wipb = (uint)f2h(PSCALE * __expf(ALPHA * xb - Mb)) * 0x10001u;

    // staging: the 128 threads of each j-quarter (waves rg0/jq and rg1/jq)
    // stage that quarter's tile. st in [0,128): so = B row, sc = 64B col grp.
    const int jb = jq * 1024;
    const int st = rg * 64 + lane;
    const int so = st >> 1;
    const int sc = (st & 1) * 32;
    const ushort* gB = WhT + ((size_t)head * FOUT + so) * NN + jb + sc;
    const ushort* gvt = vt + (size_t)head * NN + jb;
    const ushort* gzt = zt + (size_t)head * NN + jb;
    const uchar* mra = mb + (size_t)rowa * 512 + (jb >> 3);
    const uchar* mrb = mra + 16 * 512;

    uintx4 rr0, rr1, rr2, rr3;
    uintx2 mka_s, mkb_s;

    auto gload = [&](int j0) {     // j0 local to this quarter, in [0,1024)
        rr0 = *(const uintx4*)(gB + j0);
        rr1 = *(const uintx4*)(gB + j0 + 8);
        rr2 = *(const uintx4*)(gB + j0 + 16);
        rr3 = *(const uintx4*)(gB + j0 + 24);
        mka_s = *(const uintx2*)(mra + (j0 >> 3));
        mkb_s = *(const uintx2*)(mrb + (j0 >> 3));
    };
    auto lwrite = [&](int buf) {
        ushort* d = &sB[jq][buf][so * 72 + sc];
        *(uintx4*)(d)      = rr0;
        *(uintx4*)(d + 8)  = rr1;
        *(uintx4*)(d + 16) = rr2;
        *(uintx4*)(d + 24) = rr3;
    };

    uintx4 v0a, v0b, z0a, z0b;
    uintx4 v1a, v1b, z1a, z1b;

    const half8 onesh = {(_Float16)1.f, (_Float16)1.f, (_Float16)1.f, (_Float16)1.f,
                         (_Float16)1.f, (_Float16)1.f, (_Float16)1.f, (_Float16)1.f};
    floatx4 Z = {0.f, 0.f, 0.f, 0.f};
    floatx4 C0 = Z, C1 = Z, C2 = Z, C3 = Z, Cd0 = Z;
    floatx4 C4 = Z, C5 = Z, C6 = Z, C7 = Z, Cd1 = Z;

    auto compute = [&](int buf, uintx2 mka, uintx2 mkb,
                       uintx4 vA, uintx4 vB, uintx4 zA, uintx4 zB) {
        uint m0a = mka.x >> sh8;
        uint m1a = mka.y >> sh8;
        uint m0b = mkb.x >> sh8;
        uint m1b = mkb.y >> sh8;
        half8 a0 = pgen8h(vA, zA, m0a, uipa, wipa);   // rows lm,    j 0..31
        half8 a1 = pgen8h(vB, zB, m1a, uipa, wipa);   // rows lm,    j 32..63
        half8 a2 = pgen8h(vA, zA, m0b, uipb, wipb);   // rows lm+16, j 0..31
        half8 a3 = pgen8h(vB, zB, m1b, uipb, wipb);   // rows lm+16, j 32..63
        const ushort* base = &sB[jq][buf][0];
        half8 b00 = *(const half8*)(base + (0  + lm) * 72 + sh8);
        half8 b10 = *(const half8*)(base + (16 + lm) * 72 + sh8);
        half8 b20 = *(const half8*)(base + (32 + lm) * 72 + sh8);
        half8 b30 = *(const half8*)(base + (48 + lm) * 72 + sh8);
        Cd0 = __builtin_amdgcn_mfma_f32_16x16x32_f16(a0, onesh, Cd0, 0, 0, 0);
        Cd1 = __builtin_amdgcn_mfma_f32_16x16x32_f16(a2, onesh, Cd1, 0, 0, 0);
        C0 = __builtin_amdgcn_mfma_f32_16x16x32_f16(a0, b00, C0, 0, 0, 0);
        C4 = __builtin_amdgcn_mfma_f32_16x16x32_f16(a2, b00, C4, 0, 0, 0);
        C1 = __builtin_amdgcn_mfma_f32_16x16x32_f16(a0, b10, C1, 0, 0, 0);
        C5 = __builtin_amdgcn_mfma_f32_16x16x32_f16(a2, b10, C5, 0, 0, 0);
        C2 = __builtin_amdgcn_mfma_f32_16x16x32_f16(a0, b20, C2, 0, 0, 0);
        C6 = __builtin_amdgcn_mfma_f32_16x16x32_f16(a2, b20, C6, 0, 0, 0);
        C3 = __builtin_amdgcn_mfma_f32_16x16x32_f16(a0, b30, C3, 0, 0, 0);
        C7 = __builtin_amdgcn_mfma_f32_16x16x32_f16(a2, b30, C7, 0, 0, 0);
        half8 b01 = *(const half8*)(base + (0  + lm) * 72 + 32 + sh8);
        half8 b11 = *(const half8*)(base + (16 + lm) * 72 + 32 + sh8);
        half8 b21 = *(const half8*)(base + (32 + lm) * 72 + 32 + sh8);
        half8 b31 = *(const half8*)(base + (48 + lm) * 72 + 32 + sh8);
        Cd0 = __builtin_amdgcn_mfma_f32_16x16x32_f16(a1, onesh, Cd0, 0, 0, 0);
        Cd1 = __builtin_amdgcn_mfma_f32_16x16x32_f16(a3, onesh, Cd1, 0, 0, 0);
        C0 = __builtin_amdgcn_mfma_f32_16x16x32_f16(a1, b01, C0, 0, 0, 0);
        C4 = __builtin_amdgcn_mfma_f32_16x16x32_f16(a3, b01, C4, 0, 0, 0);
        C1 = __builtin_amdgcn_mfma_f32_16x16x32_f16(a1, b11, C1, 0, 0, 0);
        C5 = __builtin_amdgcn_mfma_f32_16x16x32_f16(a3, b11, C5, 0, 0, 0);
        C2 = __builtin_amdgcn_mfma_f32_16x16x32_f16(a1, b21, C2, 0, 0, 0);
        C6 = __builtin_amdgcn_mfma_f32_16x16x32_f16(a3, b21, C6, 0, 0, 0);
        C3 = __builtin_amdgcn_mfma_f32_16x16x32_f16(a1, b31, C3, 0, 0, 0);
        C7 = __builtin_amdgcn_mfma_f32_16x16x32_f16(a3, b31, C7, 0, 0, 0);
    };

    // prologue: buf0 <- tile 0 of this quarter; rr <- tile 1; vz0 <- tile 0
    uintx2 mka0, mkb0, mka1, mkb1;
    gload(0);
    lwrite(0);
    mka0 = mka_s; mkb0 = mkb_s;
    gload(64);
    VZLOAD(0, 0);
    KEEP(rr0); KEEP(rr1); KEEP(rr2); KEEP(rr3);
    KEEP(v0a); KEEP(v0b); KEEP(z0a); KEEP(z0b);
    BARRIER();

    // main loop: 16 tiles per wave, 1 counted barrier per tile; prefetch
    // issued before compute and pinned live; loads cross the barrier.
    for (int it = 0; it < 16; it += 2) {
        // phase A: compute tile it (buf0, vz0)
        lwrite(1);                               // tile it+1 -> buf1
        mka1 = mka_s; mkb1 = mkb_s;
        gload(((it + 2) & 15) * 64);             // rr <- tile it+2
        VZLOAD(1, (it + 1) * 64);                // vz1 <- tile it+1
        compute(0, mka0, mkb0, v0a, v0b, z0a, z0b);
        KEEP(v1a); KEEP(v1b); KEEP(z1a); KEEP(z1b);
        KEEP(rr0); KEEP(rr1); KEEP(rr2); KEEP(rr3);
        BARRIER();
        // phase B: compute tile it+1 (buf1, vz1)
        lwrite(0);                               // tile it+2 -> buf0
        mka0 = mka_s; mkb0 = mkb_s;
        gload(((it + 3) & 15) * 64);             // rr <- tile it+3
        VZLOAD(0, ((it + 2) & 15) * 64);         // vz0 <- tile it+2
        compute(1, mka1, mkb1, v1a, v1b, z1a, z1b);
        KEEP(v0a); KEEP(v0b); KEEP(z0a); KEEP(z0b);
        KEEP(rr0); KEEP(rr1); KEEP(rr2); KEEP(rr3);
        BARRIER();
    }

    // merge j-quarters: jq=1..3 publish partials via LDS, jq=0 accumulates.
    // lane stride 44 dwords (16B-aligned); 3 x 128 x 44 x 4B = 67.6KB <= 73.7KB
    float* mg = (float*)&sB[0][0][0];
    const int mi = ((jq - 1) * 128 + rg * 64 + lane) * 44;
    if (jq > 0) {
        float* p = &mg[mi];
        *(floatx4*)(p + 0)  = C0;  *(floatx4*)(p + 4)  = C1;
        *(floatx4*)(p + 8)  = C2;  *(floatx4*)(p + 12) = C3;
        *(floatx4*)(p + 16) = C4;  *(floatx4*)(p + 20) = C5;
        *(floatx4*)(p + 24) = C6;  *(floatx4*)(p + 28) = C7;
        *(floatx4*)(p + 32) = Cd0; *(floatx4*)(p + 36) = Cd1;
    }
    BARRIER();
    if (jq == 0) {
#pragma unroll
        for (int s = 0; s < 3; s++) {
            const float* p = &mg[(s * 128 + rg * 64 + lane) * 44];
            C0 += *(const floatx4*)(p + 0);   C1 += *(const floatx4*)(p + 4);
            C2 += *(const floatx4*)(p + 8);   C3 += *(const floatx4*)(p + 12);
            C4 += *(const floatx4*)(p + 16);  C5 += *(const floatx4*)(p + 20);
            C6 += *(const floatx4*)(p + 24);  C7 += *(const floatx4*)(p + 28);
            Cd0 += *(const floatx4*)(p + 32); Cd1 += *(const floatx4*)(p + 36);
        }
        // epilogue: normalize, elu, store (two row groups per lane)
        const int isbf = detect_bf16(hraw);
#pragma unroll
        for (int r = 0; r < 4; r++) {
            int ra = ibase + rg * 32 + lq * 4 + r;
            int rb = ra + 16;
            float inva = 1.f / Cd0[r];
            float invb = 1.f / Cd1[r];
            float x0 = C0[r] * inva; x0 = (x0 > 0.f) ? x0 : __expf(x0) - 1.f;
            float x1 = C1[r] * inva; x1 = (x1 > 0.f) ? x1 : __expf(x1) - 1.f;
            float x2 = C2[r] * inva; x2 = (x2 > 0.f) ? x2 : __expf(x2) - 1.f;
            float x3 = C3[r] * inva; x3 = (x3 > 0.f) ? x3 : __expf(x3) - 1.f;
            float y0 = C4[r] * invb; y0 = (y0 > 0.f) ? y0 : __expf(y0) - 1.f;
            float y1 = C5[r] * invb; y1 = (y1 > 0.f) ? y1 : __expf(y1) - 1.f;
            float y2 = C6[r] * invb; y2 = (y2 > 0.f) ? y2 : __expf(y2) - 1.f;
            float y3 = C7[r] * invb; y3 = (y3 > 0.f) ? y3 : __expf(y3) - 1.f;
            size_t basea = (size_t)ra * (NH * FOUT) + head * FOUT + lm;
            size_t baseb = (size_t)rb * (NH * FOUT) + head * FOUT + lm;
            if (isbf) {
                ushort* o = (ushort*)outv;
                o[basea + 0]  = f2bf(x0);
                o[basea + 16] = f2bf(x1);
                o[basea + 32] = f2bf(x2);
                o[basea + 48] = f2bf(x3);
                o[baseb + 0]  = f2bf(y0);
                o[baseb + 16] = f2bf(y1);
                o[baseb + 32] = f2bf(y2);
                o[baseb + 48] = f2bf(y3);
            } else {
                float* o = (float*)outv;
                o[basea + 0]  = x0;
                o[basea + 16] = x1;
                o[basea + 32] = x2;
                o[basea + 48] = x3;
                o[baseb + 0]  = y0;
                o[baseb + 16] = y1;
                o[baseb + 32] = y2;
                o[baseb + 48] = y3;
            }
        }
    }
}

extern "C" void kernel_launch(void* const* d_in, const int* in_sizes, int n_in,
                              void* d_out, int out_size, void* d_ws, size_t ws_size,
                              hipStream_t stream)
{
    const void* hraw = d_in[0];
    const int*  mask = (const int*)d_in[1];
    const void* Wraw = d_in[2];
    const void* bWr  = d_in[3];
    const void* alr  = d_in[4];
    const void* arr  = d_in[5];
    const void* bAr  = d_in[6];

    char* w = (char*)d_ws;
    ushort* bh   = (ushort*)w;                  w += (size_t)NN * FIN * 2;        // 4 MB
    ushort* WT   = (ushort*)w;                  w += (size_t)NH * FOUT * FIN * 2; // 512 KB
    ushort* WhT  = (ushort*)w;                  w += (size_t)NH * FOUT * NN * 2;  // 4 MB
    float*  el   = (float*)w;                   w += (size_t)NH * NN * 4;
    float*  er   = (float*)w;                   w += (size_t)NH * NN * 4;
    float*  Kh   = (float*)w;                   w += 64;
    ushort* vt   = (ushort*)w;                  w += (size_t)NH * NN * 4;  // fp16, slack kept
    ushort* zt   = (ushort*)w;                  w += (size_t)NH * NN * 4;
    uchar*  mb   = (uchar*)w;                   w += (size_t)NN * 512;            // 2 MB

    prep_kernel<<<PM_BLKS + CV_BLKS + TW_BLKS, 256, 0, stream>>>(
        mask, mb, hraw, bh, Wraw, WT);
    wh_kernel<<<dim3(NN / 64, NH), 256, 0, stream>>>(bh, WT, bWr, alr, arr, bAr,
                                                     (const ushort*)hraw, WhT, el, er);
    khv_kernel<<<64, 256, 0, stream>>>(er, Kh, vt, zt);
    attn_kernel<<<NN / 64 * NH, 512, 0, stream>>>(mb, WhT, el, Kh, vt, zt,
                                                  (const ushort*)hraw, d_out);
}

// Round 14
// 183.092 us; speedup vs baseline: 1.0595x; 1.0552x over previous
//
#include <hip/hip_runtime.h>
#include <hip/hip_bf16.h>
#include <hip/hip_fp16.h>

#define NN 4096
#define FIN 512
#define FOUT 64
#define NH 8
#define ALPHA 0.2f
#define PSCALE 4096.0f   // 2^12 row-invariant P scale (C/Cd invariant)

typedef unsigned int uint;
typedef unsigned short ushort;
typedef unsigned char uchar;
typedef unsigned long long ull;
typedef __attribute__((ext_vector_type(8))) short short8;
typedef __attribute__((ext_vector_type(8))) _Float16 half8;
typedef __attribute__((ext_vector_type(4))) float floatx4;
typedef __attribute__((ext_vector_type(4))) uint uintx4;
typedef __attribute__((ext_vector_type(2))) uint uintx2;

__device__ __forceinline__ float bf2f(ushort s) { return __uint_as_float(((uint)s) << 16); }
__device__ __forceinline__ ushort f2bf(float f) {
    uint u = __float_as_uint(f);
    u += 0x7fffu + ((u >> 16) & 1u);   // RNE
    return (ushort)(u >> 16);
}
__device__ __forceinline__ ushort f2h(float f) {
    return __half_as_ushort(__float2half_rn(f));
}

// inline dtype probe: wave-uniform, deterministic (same 64 samples everywhere)
__device__ __forceinline__ int detect_bf16(const ushort* __restrict__ hraw) {
    int lane = threadIdx.x & 63;
    float a = fabsf(bf2f(hraw[2 * lane]));
    ull bal = __ballot(a >= 1e-3f && a <= 100.0f);
    return __popcll(bal) >= 32;
}

// ---------------------------------------------------------------------------
// Fused prep: [0,8192) packmask | [8192,9216) convert h (8 elem/thread) |
//             [9216,9248) transw   (bf16 WT)
// ---------------------------------------------------------------------------
#define PM_BLKS 8192
#define CV_BLKS 1024
#define TW_BLKS 32

__global__ __launch_bounds__(256) void prep_kernel(
    const int* __restrict__ mask, uchar* __restrict__ mb,
    const void* __restrict__ hraw, ushort* __restrict__ bh,
    const void* __restrict__ Wraw, ushort* __restrict__ WT)
{
    const int b = blockIdx.x, t = threadIdx.x;
    if (b < PM_BLKS) {
        size_t gid = (size_t)b * 256 + t;
        const int* p = mask + gid * 8;
        int4 aa = *(const int4*)p;
        int4 bb = *(const int4*)(p + 4);
        uint by = (uint)(aa.x > 0)        | ((uint)(aa.y > 0) << 1)
                | ((uint)(aa.z > 0) << 2) | ((uint)(aa.w > 0) << 3)
                | ((uint)(bb.x > 0) << 4) | ((uint)(bb.y > 0) << 5)
                | ((uint)(bb.z > 0) << 6) | ((uint)(bb.w > 0) << 7);
        mb[gid] = (uchar)by;
    } else if (b < PM_BLKS + CV_BLKS) {
        int isbf = detect_bf16((const ushort*)hraw);
        size_t e0 = ((size_t)(b - PM_BLKS) * 256 + t) * 8;
        if (isbf) {
            *(uint4*)(bh + e0) = *(const uint4*)((const ushort*)hraw + e0);
        } else {
            const float* s = (const float*)hraw + e0;
            float4 f0 = *(const float4*)s;
            float4 f1 = *(const float4*)(s + 4);
            uint4 o;
            o.x = (uint)f2bf(f0.x) | ((uint)f2bf(f0.y) << 16);
            o.y = (uint)f2bf(f0.z) | ((uint)f2bf(f0.w) << 16);
            o.z = (uint)f2bf(f1.x) | ((uint)f2bf(f1.y) << 16);
            o.w = (uint)f2bf(f1.z) | ((uint)f2bf(f1.w) << 16);
            *(uint4*)(bh + e0) = o;
        }
    } else {
        int isbf = detect_bf16((const ushort*)hraw);
        int b2 = b - PM_BLKS - CV_BLKS;
        int h = b2 >> 2, kq = b2 & 3;
        int o = t & 63, sub = t >> 6;
        int kbase = kq * 128 + sub * 32;
        uint pk[16];
#pragma unroll
        for (int kk = 0; kk < 32; kk += 2) {
            float v0, v1;
            size_t s0 = ((size_t)h * FIN + kbase + kk) * FOUT + o;
            size_t s1 = s0 + FOUT;
            if (isbf) { v0 = bf2f(((const ushort*)Wraw)[s0]); v1 = bf2f(((const ushort*)Wraw)[s1]); }
            else      { v0 = ((const float*)Wraw)[s0];        v1 = ((const float*)Wraw)[s1]; }
            pk[kk >> 1] = (uint)f2bf(v0) | ((uint)f2bf(v1) << 16);
        }
        ushort* dst = WT + ((size_t)h * FOUT + o) * FIN + kbase;
#pragma unroll
        for (int q = 0; q < 4; q++)
            *(uint4*)(dst + q * 8) = make_uint4(pk[q*4], pk[q*4+1], pk[q*4+2], pk[q*4+3]);
    }
}

// per-head tables (fp16): Kh = max_j er'; v_j = e^{er-Kh}; z_j = e^{alpha(er-Kh)}
__global__ __launch_bounds__(256) void khv_kernel(const float* __restrict__ er,
                                                  float* __restrict__ Kh,
                                                  ushort* __restrict__ vt,
                                                  ushort* __restrict__ zt) {
    __shared__ float red[256];
    int h = blockIdx.x >> 3, sl = blockIdx.x & 7, t = threadIdx.x;
    float m = -3.0e38f;
    for (int j = t; j < NN; j += 256) m = fmaxf(m, er[(size_t)h * NN + j]);
    red[t] = m;
    __syncthreads();
    for (int s = 128; s >= 1; s >>= 1) {
        if (t < s) red[t] = fmaxf(red[t], red[t + s]);
        __syncthreads();
    }
    float kh = red[0];
    if (t == 0 && sl == 0) Kh[h] = kh;
    int j = sl * 512 + t;
#pragma unroll
    for (int q = 0; q < 2; q++, j += 256) {
        float d = er[(size_t)h * NN + j] - kh;
        vt[(size_t)h * NN + j] = f2h(__expf(d));
        zt[(size_t)h * NN + j] = f2h(__expf(ALPHA * d));
    }
}

// ---------------------------------------------------------------------------
// Stage 1 (MFMA): Wh = h*W + bW; WhT[h][o][n] fp16; el/er dots (f32).
// bf16 A, bf16 WT, bf16 MFMA (fast path); only WhT output fp16.
// ---------------------------------------------------------------------------
__global__ __launch_bounds__(256) void wh_kernel(
    const ushort* __restrict__ hmat, const ushort* __restrict__ WT,
    const void* __restrict__ bWr, const void* __restrict__ alr,
    const void* __restrict__ arr, const void* __restrict__ bAr,
    const ushort* __restrict__ hraw,
    ushort* __restrict__ WhT, float* __restrict__ el, float* __restrict__ er)
{
    __shared__ __align__(16) ushort sT[64][72];
    const int t = threadIdx.x, lane = t & 63, wid = t >> 6;
    const int head = blockIdx.y, rbase = blockIdx.x * 64;
    const int lm = lane & 15, lq = lane >> 4;

    floatx4 C[4];
#pragma unroll
    for (int cg = 0; cg < 4; cg++) C[cg] = (floatx4){0.f, 0.f, 0.f, 0.f};

    const ushort* Ap = hmat + (size_t)(rbase + wid * 16 + lm) * FIN + lq * 8;
    const ushort* Bp = WT + (size_t)head * FOUT * FIN + (size_t)lm * FIN + lq * 8;

#pragma unroll
    for (int kc = 0; kc < 16; kc++) {
        short8 a = *(const short8*)(Ap + kc * 32);
#pragma unroll
        for (int cg = 0; cg < 4; cg++) {
            short8 b = *(const short8*)(Bp + (size_t)cg * 16 * FIN + kc * 32);
            C[cg] = __builtin_amdgcn_mfma_f32_16x16x32_bf16(a, b, C[cg], 0, 0, 0);
        }
    }

    const int isbf = detect_bf16(hraw);
    float bA = isbf ? bf2f(((const ushort*)bAr)[head]) : ((const float*)bAr)[head];
    float pel[4] = {0.f, 0.f, 0.f, 0.f}, per[4] = {0.f, 0.f, 0.f, 0.f};
#pragma unroll
    for (int cg = 0; cg < 4; cg++) {
        int o = head * FOUT + cg * 16 + lm;
        float bw = isbf ? bf2f(((const ushort*)bWr)[o]) : ((const float*)bWr)[o];
        float av = isbf ? bf2f(((const ushort*)alr)[o]) : ((const float*)alr)[o];
        float rv = isbf ? bf2f(((const ushort*)arr)[o]) : ((const float*)arr)[o];
        ushort pk[4];
#pragma unroll
        for (int r = 0; r < 4; r++) {
            float v = C[cg][r] + bw;
            pel[r] += v * av;
            per[r] += v * rv;
            pk[r] = f2h(v);                    // fp16 WhT for stage 2
        }
        ushort4 p4; p4.x = pk[0]; p4.y = pk[1]; p4.z = pk[2]; p4.w = pk[3];
        *(ushort4*)(&sT[cg * 16 + lm][wid * 16 + lq * 4]) = p4;
    }
#pragma unroll
    for (int off = 1; off < 16; off <<= 1) {
#pragma unroll
        for (int r = 0; r < 4; r++) {
            pel[r] += __shfl_xor(pel[r], off);
            per[r] += __shfl_xor(per[r], off);
        }
    }
    if (lm == 0) {
#pragma unroll
        for (int r = 0; r < 4; r++) {
            int row = rbase + wid * 16 + lq * 4 + r;
            el[(size_t)head * NN + row] = pel[r];
            er[(size_t)head * NN + row] = per[r] + bA;
        }
    }
    __syncthreads();
    {
        int o = t >> 2, ch = t & 3;
        uint4 v0 = *(const uint4*)(&sT[o][ch * 16]);
        uint4 v1 = *(const uint4*)(&sT[o][ch * 16 + 8]);
        ushort* d = WhT + ((size_t)head * FOUT + o) * NN + rbase + ch * 16;
        *(uint4*)d = v0;
        *(uint4*)(d + 8) = v1;
    }
}

// ---------------------------------------------------------------------------
// Stage 2 (R27 = R23 minus KEEPs): quarter-split abandoned (R24 spill, R26
// lockstep regression — independent 4-wave blocks/CU beat 8-wave groups).
// R23 structure: 4 waves = 2 row-groups x 2 j-halves, 32 tiles/wave, counted
// barrier (lgkmcnt(0)+s_barrier). KEEPs REMOVED: "+v" reads forced vmcnt
// waits BEFORE the barrier, partially re-creating the drain. BARRIER's
// "memory" clobber already pins load issue before the barrier; waits now
// land at next-phase use points (true counted-vmcnt cross-barrier pipeline).
// ---------------------------------------------------------------------------
__device__ __forceinline__ uint pkmul(uint a, uint b) {
    uint d; asm("v_pk_mul_f16 %0,%1,%2" : "=v"(d) : "v"(a), "v"(b)); return d;
}
__device__ __forceinline__ uint pkmax(uint a, uint b) {
    uint d; asm("v_pk_max_f16 %0,%1,%2" : "=v"(d) : "v"(a), "v"(b)); return d;
}
// bits 0,1 of a -> 0x0000FFFF / 0xFFFF0000 select words
__device__ __forceinline__ uint pmask2(uint a) {
    uint b = a & 3u;
    return ((b | (b << 15)) & 0x10001u) * 0xFFFFu;
}
__device__ __forceinline__ half8 pgen8h(uintx4 vv, uintx4 zz, uint mby,
                                        uint uip, uint wip) {
    union { uintx4 u; half8 h; } c;
    c.u.x = pkmax(pkmul(uip, vv.x), pkmul(wip, zz.x)) & pmask2(mby);
    c.u.y = pkmax(pkmul(uip, vv.y), pkmul(wip, zz.y)) & pmask2(mby >> 2);
    c.u.z = pkmax(pkmul(uip, vv.z), pkmul(wip, zz.z)) & pmask2(mby >> 4);
    c.u.w = pkmax(pkmul(uip, vv.w), pkmul(wip, zz.w)) & pmask2(mby >> 6);
    return c.h;
}

// counted barrier: LDS visibility only; vmcnt stays counted at use sites
#define BARRIER() do { asm volatile("s_waitcnt lgkmcnt(0)" ::: "memory"); \
                       __builtin_amdgcn_s_barrier(); } while (0)

#define VZLOAD(S, j0) do {                                   \
    v##S##a = *(const uintx4*)(gvt + (j0) + sh8);            \
    v##S##b = *(const uintx4*)(gvt + (j0) + 32 + sh8);       \
    z##S##a = *(const uintx4*)(gzt + (j0) + sh8);            \
    z##S##b = *(const uintx4*)(gzt + (j0) + 32 + sh8);       \
} while (0)

__global__ __launch_bounds__(256, 2) void attn_kernel(
    const uchar* __restrict__ mb,      // [NN][512] bitmask
    const ushort* __restrict__ WhT,    // [H][FOUT][NN] fp16
    const float* __restrict__ el, const float* __restrict__ Kh,
    const ushort* __restrict__ vt, const ushort* __restrict__ zt,
    const ushort* __restrict__ hraw,
    void* __restrict__ outv)
{
    __shared__ __align__(16) ushort sB[2][2][64 * 72];  // [jhalf][dbuf] tiles

    const int t = threadIdx.x, lane = t & 63, wid = t >> 6;  // 4 waves
    const int rg = wid >> 1;       // row group (32 rows each)
    const int jh = wid & 1;        // j half (0: j<2048, 1: j>=2048)
    const int b = blockIdx.x;
    const int head = b & 7;                       // XCD swizzle
    const int ibase = (b >> 3) * 64;
    const int lm = lane & 15, lq = lane >> 4;
    const int sh8 = lq * 8;

    // per-lane row constants for rows lm and lm+16 of this wave's 32 rows
    const float kh = Kh[head];
    const int rowa = ibase + rg * 32 + lm;
    const float xa = el[(size_t)head * NN + rowa] + kh;
    const float xb = el[(size_t)head * NN + rowa + 16] + kh;
    const float Ma = fmaxf(xa, ALPHA * xa);
    const float Mb = fmaxf(xb, ALPHA * xb);
    const uint uipa = (uint)f2h(PSCALE * __expf(xa - Ma)) * 0x10001u;
    const uint wipa = (uint)f2h(PSCALE * __expf(ALPHA * xa - Ma)) * 0x10001u;
    const uint uipb = (uint)f2h(PSCALE * __expf(xb - Mb)) * 0x10001u;
    const uint wipb = (uint)f2h(PSCALE * __expf(ALPHA * xb - Mb)) * 0x10001u;

    // staging: the 128 threads of each j-half stage that half's tile.
    // st in [0,128): so = B row, sc = 64B col group (2 thr per row).
    const int jb = jh * 2048;
    const int st = rg * 64 + lane;
    const int so = st >> 1;
    const int sc = (st & 1) * 32;
    const ushort* gB = WhT + ((size_t)head * FOUT + so) * NN + jb + sc;
    const ushort* gvt = vt + (size_t)head * NN + jb;
    const ushort* gzt = zt + (size_t)head * NN + jb;
    const uchar* mra = mb + (size_t)rowa * 512 + (jb >> 3);
    const uchar* mrb = mra + 16 * 512;

    uintx4 rr0, rr1, rr2, rr3;
    uintx2 mka_s, mkb_s;

    auto gload = [&](int j0) {     // j0 local to this half, in [0,2048)
        rr0 = *(const uintx4*)(gB + j0);
        rr1 = *(const uintx4*)(gB + j0 + 8);
        rr2 = *(const uintx4*)(gB + j0 + 16);
        rr3 = *(const uintx4*)(gB + j0 + 24);
        mka_s = *(const uintx2*)(mra + (j0 >> 3));
        mkb_s = *(const uintx2*)(mrb + (j0 >> 3));
    };
    auto lwrite = [&](int buf) {
        ushort* d = &sB[jh][buf][so * 72 + sc];
        *(uintx4*)(d)      = rr0;
        *(uintx4*)(d + 8)  = rr1;
        *(uintx4*)(d + 16) = rr2;
        *(uintx4*)(d + 24) = rr3;
    };

    uintx4 v0a, v0b, z0a, z0b;
    uintx4 v1a, v1b, z1a, z1b;

    const half8 onesh = {(_Float16)1.f, (_Float16)1.f, (_Float16)1.f, (_Float16)1.f,
                         (_Float16)1.f, (_Float16)1.f, (_Float16)1.f, (_Float16)1.f};
    floatx4 Z = {0.f, 0.f, 0.f, 0.f};
    floatx4 C0 = Z, C1 = Z, C2 = Z, C3 = Z, Cd0 = Z;
    floatx4 C4 = Z, C5 = Z, C6 = Z, C7 = Z, Cd1 = Z;

    auto compute = [&](int buf, uintx2 mka, uintx2 mkb,
                       uintx4 vA, uintx4 vB, uintx4 zA, uintx4 zB) {
        uint m0a = mka.x >> sh8;
        uint m1a = mka.y >> sh8;
        uint m0b = mkb.x >> sh8;
        uint m1b = mkb.y >> sh8;
        half8 a0 = pgen8h(vA, zA, m0a, uipa, wipa);   // rows lm,    j 0..31
        half8 a1 = pgen8h(vB, zB, m1a, uipa, wipa);   // rows lm,    j 32..63
        half8 a2 = pgen8h(vA, zA, m0b, uipb, wipb);   // rows lm+16, j 0..31
        half8 a3 = pgen8h(vB, zB, m1b, uipb, wipb);   // rows lm+16, j 32..63
        const ushort* base = &sB[jh][buf][0];
        half8 b00 = *(const half8*)(base + (0  + lm) * 72 + sh8);
        half8 b10 = *(const half8*)(base + (16 + lm) * 72 + sh8);
        half8 b20 = *(const half8*)(base + (32 + lm) * 72 + sh8);
        half8 b30 = *(const half8*)(base + (48 + lm) * 72 + sh8);
        Cd0 = __builtin_amdgcn_mfma_f32_16x16x32_f16(a0, onesh, Cd0, 0, 0, 0);
        Cd1 = __builtin_amdgcn_mfma_f32_16x16x32_f16(a2, onesh, Cd1, 0, 0, 0);
        C0 = __builtin_amdgcn_mfma_f32_16x16x32_f16(a0, b00, C0, 0, 0, 0);
        C4 = __builtin_amdgcn_mfma_f32_16x16x32_f16(a2, b00, C4, 0, 0, 0);
        C1 = __builtin_amdgcn_mfma_f32_16x16x32_f16(a0, b10, C1, 0, 0, 0);
        C5 = __builtin_amdgcn_mfma_f32_16x16x32_f16(a2, b10, C5, 0, 0, 0);
        C2 = __builtin_amdgcn_mfma_f32_16x16x32_f16(a0, b20, C2, 0, 0, 0);
        C6 = __builtin_amdgcn_mfma_f32_16x16x32_f16(a2, b20, C6, 0, 0, 0);
        C3 = __builtin_amdgcn_mfma_f32_16x16x32_f16(a0, b30, C3, 0, 0, 0);
        C7 = __builtin_amdgcn_mfma_f32_16x16x32_f16(a2, b30, C7, 0, 0, 0);
        half8 b01 = *(const half8*)(base + (0  + lm) * 72 + 32 + sh8);
        half8 b11 = *(const half8*)(base + (16 + lm) * 72 + 32 + sh8);
        half8 b21 = *(const half8*)(base + (32 + lm) * 72 + 32 + sh8);
        half8 b31 = *(const half8*)(base + (48 + lm) * 72 + 32 + sh8);
        Cd0 = __builtin_amdgcn_mfma_f32_16x16x32_f16(a1, onesh, Cd0, 0, 0, 0);
        Cd1 = __builtin_amdgcn_mfma_f32_16x16x32_f16(a3, onesh, Cd1, 0, 0, 0);
        C0 = __builtin_amdgcn_mfma_f32_16x16x32_f16(a1, b01, C0, 0, 0, 0);
        C4 = __builtin_amdgcn_mfma_f32_16x16x32_f16(a3, b01, C4, 0, 0, 0);
        C1 = __builtin_amdgcn_mfma_f32_16x16x32_f16(a1, b11, C1, 0, 0, 0);
        C5 = __builtin_amdgcn_mfma_f32_16x16x32_f16(a3, b11, C5, 0, 0, 0);
        C2 = __builtin_amdgcn_mfma_f32_16x16x32_f16(a1, b21, C2, 0, 0, 0);
        C6 = __builtin_amdgcn_mfma_f32_16x16x32_f16(a3, b21, C6, 0, 0, 0);
        C3 = __builtin_amdgcn_mfma_f32_16x16x32_f16(a1, b31, C3, 0, 0, 0);
        C7 = __builtin_amdgcn_mfma_f32_16x16x32_f16(a3, b31, C7, 0, 0, 0);
    };

    // prologue: buf0 <- tile 0 of this half; rr <- tile 1; vz0 <- tile 0
    uintx2 mka0, mkb0, mka1, mkb1;
    gload(0);
    lwrite(0);
    mka0 = mka_s; mkb0 = mkb_s;
    gload(64);
    VZLOAD(0, 0);
    BARRIER();

    // main loop: 32 tiles per wave, 1 counted barrier per tile; prefetch
    // issued before compute; loads cross the barrier, waits land at uses.
    for (int it = 0; it < 32; it += 2) {
        // phase A: compute tile it (buf0, vz0)
        lwrite(1);                               // tile it+1 -> buf1
        mka1 = mka_s; mkb1 = mkb_s;
        gload(((it + 2) & 31) * 64);             // rr <- tile it+2
        VZLOAD(1, (it + 1) * 64);                // vz1 <- tile it+1
        compute(0, mka0, mkb0, v0a, v0b, z0a, z0b);
        BARRIER();
        // phase B: compute tile it+1 (buf1, vz1)
        lwrite(0);                               // tile it+2 -> buf0
        mka0 = mka_s; mkb0 = mkb_s;
        gload(((it + 3) & 31) * 64);             // rr <- tile it+3
        VZLOAD(0, ((it + 2) & 31) * 64);         // vz0 <- tile it+2
        compute(1, mka1, mkb1, v1a, v1b, z1a, z1b);
        BARRIER();
    }

    // merge j-halves: jh=1 waves publish partials via LDS, jh=0 accumulate.
    // lane stride 44 dwords (16B-aligned, odd/4 stride -> spread banks).
    float* mg = (float*)&sB[0][0][0];   // 22528 B needed <= 36864 B
    const int mi = (rg * 64 + lane) * 44;
    if (jh == 1) {
        float* p = &mg[mi];
        *(floatx4*)(p + 0)  = C0;  *(floatx4*)(p + 4)  = C1;
        *(floatx4*)(p + 8)  = C2;  *(floatx4*)(p + 12) = C3;
        *(floatx4*)(p + 16) = C4;  *(floatx4*)(p + 20) = C5;
        *(floatx4*)(p + 24) = C6;  *(floatx4*)(p + 28) = C7;
        *(floatx4*)(p + 32) = Cd0; *(floatx4*)(p + 36) = Cd1;
    }
    BARRIER();
    if (jh == 0) {
        const float* p = &mg[mi];
        C0 += *(const floatx4*)(p + 0);   C1 += *(const floatx4*)(p + 4);
        C2 += *(const floatx4*)(p + 8);   C3 += *(const floatx4*)(p + 12);
        C4 += *(const floatx4*)(p + 16);  C5 += *(const floatx4*)(p + 20);
        C6 += *(const floatx4*)(p + 24);  C7 += *(const floatx4*)(p + 28);
        Cd0 += *(const floatx4*)(p + 32); Cd1 += *(const floatx4*)(p + 36);

        // epilogue: normalize, elu, store (two row groups per lane)
        const int isbf = detect_bf16(hraw);
#pragma unroll
        for (int r = 0; r < 4; r++) {
            int ra = ibase + rg * 32 + lq * 4 + r;
            int rb = ra + 16;
            float inva = 1.f / Cd0[r];
            float invb = 1.f / Cd1[r];
            float x0 = C0[r] * inva; x0 = (x0 > 0.f) ? x0 : __expf(x0) - 1.f;
            float x1 = C1[r] * inva; x1 = (x1 > 0.f) ? x1 : __expf(x1) - 1.f;
            float x2 = C2[r] * inva; x2 = (x2 > 0.f) ? x2 : __expf(x2) - 1.f;
            float x3 = C3[r] * inva; x3 = (x3 > 0.f) ? x3 : __expf(x3) - 1.f;
            float y0 = C4[r] * invb; y0 = (y0 > 0.f) ? y0 : __expf(y0) - 1.f;
            float y1 = C5[r] * invb; y1 = (y1 > 0.f) ? y1 : __expf(y1) - 1.f;
            float y2 = C6[r] * invb; y2 = (y2 > 0.f) ? y2 : __expf(y2) - 1.f;
            float y3 = C7[r] * invb; y3 = (y3 > 0.f) ? y3 : __expf(y3) - 1.f;
            size_t basea = (size_t)ra * (NH * FOUT) + head * FOUT + lm;
            size_t baseb = (size_t)rb * (NH * FOUT) + head * FOUT + lm;
            if (isbf) {
                ushort* o = (ushort*)outv;
                o[basea + 0]  = f2bf(x0);
                o[basea + 16] = f2bf(x1);
                o[basea + 32] = f2bf(x2);
                o[basea + 48] = f2bf(x3);
                o[baseb + 0]  = f2bf(y0);
                o[baseb + 16] = f2bf(y1);
                o[baseb + 32] = f2bf(y2);
                o[baseb + 48] = f2bf(y3);
            } else {
                float* o = (float*)outv;
                o[basea + 0]  = x0;
                o[basea + 16] = x1;
                o[basea + 32] = x2;
                o[basea + 48] = x3;
                o[baseb + 0]  = y0;
                o[baseb + 16] = y1;
                o[baseb + 32] = y2;
                o[baseb + 48] = y3;
            }
        }
    }
}

extern "C" void kernel_launch(void* const* d_in, const int* in_sizes, int n_in,
                              void* d_out, int out_size, void* d_ws, size_t ws_size,
                              hipStream_t stream)
{
    const void* hraw = d_in[0];
    const int*  mask = (const int*)d_in[1];
    const void* Wraw = d_in[2];
    const void* bWr  = d_in[3];
    const void* alr  = d_in[4];
    const void* arr  = d_in[5];
    const void* bAr  = d_in[6];

    char* w = (char*)d_ws;
    ushort* bh   = (ushort*)w;                  w += (size_t)NN * FIN * 2;        // 4 MB
    ushort* WT   = (ushort*)w;                  w += (size_t)NH * FOUT * FIN * 2; // 512 KB
    ushort* WhT  = (ushort*)w;                  w += (size_t)NH * FOUT * NN * 2;  // 4 MB
    float*  el   = (float*)w;                   w += (size_t)NH * NN * 4;
    float*  er   = (float*)w;                   w += (size_t)NH * NN * 4;
    float*  Kh   = (float*)w;                   w += 64;
    ushort* vt   = (ushort*)w;                  w += (size_t)NH * NN * 4;  // fp16, slack kept
    ushort* zt   = (ushort*)w;                  w += (size_t)NH * NN * 4;
    uchar*  mb   = (uchar*)w;                   w += (size_t)NN * 512;            // 2 MB

    prep_kernel<<<PM_BLKS + CV_BLKS + TW_BLKS, 256, 0, stream>>>(
        mask, mb, hraw, bh, Wraw, WT);
    wh_kernel<<<dim3(NN / 64, NH), 256, 0, stream>>>(bh, WT, bWr, alr, arr, bAr,
                                                     (const ushort*)hraw, WhT, el, er);
    khv_kernel<<<64, 256, 0, stream>>>(er, Kh, vt, zt);
    attn_kernel<<<NN / 64 * NH, 256, 0, stream>>>(mb, WhT, el, Kh, vt, zt,
                                                  (const ushort*)hraw, d_out);
}

// Round 15
// 178.387 us; speedup vs baseline: 1.0875x; 1.0264x over previous
//
#include <hip/hip_runtime.h>
#include <hip/hip_bf16.h>
#include <hip/hip_fp16.h>

#define NN 4096
#define FIN 512
#define FOUT 64
#define NH 8
#define ALPHA 0.2f
#define PSCALE 4096.0f   // 2^12 row-invariant P scale (C/Cd invariant)

typedef unsigned int uint;
typedef unsigned short ushort;
typedef unsigned char uchar;
typedef unsigned long long ull;
typedef __attribute__((ext_vector_type(8))) short short8;
typedef __attribute__((ext_vector_type(8))) _Float16 half8;
typedef __attribute__((ext_vector_type(4))) float floatx4;
typedef __attribute__((ext_vector_type(4))) uint uintx4;
typedef __attribute__((ext_vector_type(2))) uint uintx2;

__device__ __forceinline__ float bf2f(ushort s) { return __uint_as_float(((uint)s) << 16); }
__device__ __forceinline__ ushort f2bf(float f) {
    uint u = __float_as_uint(f);
    u += 0x7fffu + ((u >> 16) & 1u);   // RNE
    return (ushort)(u >> 16);
}
__device__ __forceinline__ ushort f2h(float f) {
    return __half_as_ushort(__float2half_rn(f));
}

// inline dtype probe: wave-uniform, deterministic (same 64 samples everywhere)
__device__ __forceinline__ int detect_bf16(const ushort* __restrict__ hraw) {
    int lane = threadIdx.x & 63;
    float a = fabsf(bf2f(hraw[2 * lane]));
    ull bal = __ballot(a >= 1e-3f && a <= 100.0f);
    return __popcll(bal) >= 32;
}

// ---------------------------------------------------------------------------
// Fused prep: [0,2048) packmask (BW-tuned: 128B/thread, uint store) |
//             [2048,3072) convert h | [3072,3104) transw (bf16 WT)
// ---------------------------------------------------------------------------
#define PM_BLKS 2048
#define CV_BLKS 1024
#define TW_BLKS 32

__global__ __launch_bounds__(256) void prep_kernel(
    const int* __restrict__ mask, uchar* __restrict__ mb,
    const void* __restrict__ hraw, ushort* __restrict__ bh,
    const void* __restrict__ Wraw, ushort* __restrict__ WT)
{
    const int b = blockIdx.x, t = threadIdx.x;
    if (b < PM_BLKS) {
        // each thread: 32 consecutive ints (128B, 8x int4 -> deep ILP),
        // one uint store (4 mask bytes). mb layout identical to before.
        size_t tid = (size_t)b * 256 + t;
        const int* p = mask + tid * 32;
        uint out = 0;
#pragma unroll
        for (int q = 0; q < 4; q++) {
            int4 aa = *(const int4*)(p + q * 8);
            int4 bb = *(const int4*)(p + q * 8 + 4);
            uint by = (uint)(aa.x > 0)        | ((uint)(aa.y > 0) << 1)
                    | ((uint)(aa.z > 0) << 2) | ((uint)(aa.w > 0) << 3)
                    | ((uint)(bb.x > 0) << 4) | ((uint)(bb.y > 0) << 5)
                    | ((uint)(bb.z > 0) << 6) | ((uint)(bb.w > 0) << 7);
            out |= by << (q * 8);
        }
        ((uint*)mb)[tid] = out;
    } else if (b < PM_BLKS + CV_BLKS) {
        int isbf = detect_bf16((const ushort*)hraw);
        size_t e0 = ((size_t)(b - PM_BLKS) * 256 + t) * 8;
        if (isbf) {
            *(uint4*)(bh + e0) = *(const uint4*)((const ushort*)hraw + e0);
        } else {
            const float* s = (const float*)hraw + e0;
            float4 f0 = *(const float4*)s;
            float4 f1 = *(const float4*)(s + 4);
            uint4 o;
            o.x = (uint)f2bf(f0.x) | ((uint)f2bf(f0.y) << 16);
            o.y = (uint)f2bf(f0.z) | ((uint)f2bf(f0.w) << 16);
            o.z = (uint)f2bf(f1.x) | ((uint)f2bf(f1.y) << 16);
            o.w = (uint)f2bf(f1.z) | ((uint)f2bf(f1.w) << 16);
            *(uint4*)(bh + e0) = o;
        }
    } else {
        int isbf = detect_bf16((const ushort*)hraw);
        int b2 = b - PM_BLKS - CV_BLKS;
        int h = b2 >> 2, kq = b2 & 3;
        int o = t & 63, sub = t >> 6;
        int kbase = kq * 128 + sub * 32;
        uint pk[16];
#pragma unroll
        for (int kk = 0; kk < 32; kk += 2) {
            float v0, v1;
            size_t s0 = ((size_t)h * FIN + kbase + kk) * FOUT + o;
            size_t s1 = s0 + FOUT;
            if (isbf) { v0 = bf2f(((const ushort*)Wraw)[s0]); v1 = bf2f(((const ushort*)Wraw)[s1]); }
            else      { v0 = ((const float*)Wraw)[s0];        v1 = ((const float*)Wraw)[s1]; }
            pk[kk >> 1] = (uint)f2bf(v0) | ((uint)f2bf(v1) << 16);
        }
        ushort* dst = WT + ((size_t)h * FOUT + o) * FIN + kbase;
#pragma unroll
        for (int q = 0; q < 4; q++)
            *(uint4*)(dst + q * 8) = make_uint4(pk[q*4], pk[q*4+1], pk[q*4+2], pk[q*4+3]);
    }
}

// per-head tables (fp16): Kh = max_j er'; v_j = e^{er-Kh}; z_j = e^{alpha(er-Kh)}
__global__ __launch_bounds__(256) void khv_kernel(const float* __restrict__ er,
                                                  float* __restrict__ Kh,
                                                  ushort* __restrict__ vt,
                                                  ushort* __restrict__ zt) {
    __shared__ float red[256];
    int h = blockIdx.x >> 3, sl = blockIdx.x & 7, t = threadIdx.x;
    float m = -3.0e38f;
    for (int j = t; j < NN; j += 256) m = fmaxf(m, er[(size_t)h * NN + j]);
    red[t] = m;
    __syncthreads();
    for (int s = 128; s >= 1; s >>= 1) {
        if (t < s) red[t] = fmaxf(red[t], red[t + s]);
        __syncthreads();
    }
    float kh = red[0];
    if (t == 0 && sl == 0) Kh[h] = kh;
    int j = sl * 512 + t;
#pragma unroll
    for (int q = 0; q < 2; q++, j += 256) {
        float d = er[(size_t)h * NN + j] - kh;
        vt[(size_t)h * NN + j] = f2h(__expf(d));
        zt[(size_t)h * NN + j] = f2h(__expf(ALPHA * d));
    }
}

// ---------------------------------------------------------------------------
// Stage 1 (MFMA): Wh = h*W + bW; WhT[h][o][n] fp16; el/er dots (f32).
// bf16 A, bf16 WT, bf16 MFMA (fast path); only WhT output fp16.
// ---------------------------------------------------------------------------
__global__ __launch_bounds__(256) void wh_kernel(
    const ushort* __restrict__ hmat, const ushort* __restrict__ WT,
    const void* __restrict__ bWr, const void* __restrict__ alr,
    const void* __restrict__ arr, const void* __restrict__ bAr,
    const ushort* __restrict__ hraw,
    ushort* __restrict__ WhT, float* __restrict__ el, float* __restrict__ er)
{
    __shared__ __align__(16) ushort sT[64][72];
    const int t = threadIdx.x, lane = t & 63, wid = t >> 6;
    const int head = blockIdx.y, rbase = blockIdx.x * 64;
    const int lm = lane & 15, lq = lane >> 4;

    floatx4 C[4];
#pragma unroll
    for (int cg = 0; cg < 4; cg++) C[cg] = (floatx4){0.f, 0.f, 0.f, 0.f};

    const ushort* Ap = hmat + (size_t)(rbase + wid * 16 + lm) * FIN + lq * 8;
    const ushort* Bp = WT + (size_t)head * FOUT * FIN + (size_t)lm * FIN + lq * 8;

#pragma unroll
    for (int kc = 0; kc < 16; kc++) {
        short8 a = *(const short8*)(Ap + kc * 32);
#pragma unroll
        for (int cg = 0; cg < 4; cg++) {
            short8 b = *(const short8*)(Bp + (size_t)cg * 16 * FIN + kc * 32);
            C[cg] = __builtin_amdgcn_mfma_f32_16x16x32_bf16(a, b, C[cg], 0, 0, 0);
        }
    }

    const int isbf = detect_bf16(hraw);
    float bA = isbf ? bf2f(((const ushort*)bAr)[head]) : ((const float*)bAr)[head];
    float pel[4] = {0.f, 0.f, 0.f, 0.f}, per[4] = {0.f, 0.f, 0.f, 0.f};
#pragma unroll
    for (int cg = 0; cg < 4; cg++) {
        int o = head * FOUT + cg * 16 + lm;
        float bw = isbf ? bf2f(((const ushort*)bWr)[o]) : ((const float*)bWr)[o];
        float av = isbf ? bf2f(((const ushort*)alr)[o]) : ((const float*)alr)[o];
        float rv = isbf ? bf2f(((const ushort*)arr)[o]) : ((const float*)arr)[o];
        ushort pk[4];
#pragma unroll
        for (int r = 0; r < 4; r++) {
            float v = C[cg][r] + bw;
            pel[r] += v * av;
            per[r] += v * rv;
            pk[r] = f2h(v);                    // fp16 WhT for stage 2
        }
        ushort4 p4; p4.x = pk[0]; p4.y = pk[1]; p4.z = pk[2]; p4.w = pk[3];
        *(ushort4*)(&sT[cg * 16 + lm][wid * 16 + lq * 4]) = p4;
    }
#pragma unroll
    for (int off = 1; off < 16; off <<= 1) {
#pragma unroll
        for (int r = 0; r < 4; r++) {
            pel[r] += __shfl_xor(pel[r], off);
            per[r] += __shfl_xor(per[r], off);
        }
    }
    if (lm == 0) {
#pragma unroll
        for (int r = 0; r < 4; r++) {
            int row = rbase + wid * 16 + lq * 4 + r;
            el[(size_t)head * NN + row] = pel[r];
            er[(size_t)head * NN + row] = per[r] + bA;
        }
    }
    __syncthreads();
    {
        int o = t >> 2, ch = t & 3;
        uint4 v0 = *(const uint4*)(&sT[o][ch * 16]);
        uint4 v1 = *(const uint4*)(&sT[o][ch * 16 + 8]);
        ushort* d = WhT + ((size_t)head * FOUT + o) * NN + rbase + ch * 16;
        *(uint4*)d = v0;
        *(uint4*)(d + 8) = v1;
    }
}

// ---------------------------------------------------------------------------
// Stage 2 (R28 = R23 byte-exact attn): counted barrier + KEEPs (both proven:
// R23=49.3 vs R27-no-KEEPs=53.1 vs R22-full-drain=53.4). KEEPs force early
// load issue (compiler otherwise sinks loads to uses, exposing L2 latency);
// the counted barrier (lgkmcnt-only) lets them stay in flight across it.
// Quarter-split abandoned (R24 spill; R26 8-wave lockstep regression —
// two independent 4-wave blocks/CU beat one 8-wave group).
// ---------------------------------------------------------------------------
__device__ __forceinline__ uint pkmul(uint a, uint b) {
    uint d; asm("v_pk_mul_f16 %0,%1,%2" : "=v"(d) : "v"(a), "v"(b)); return d;
}
__device__ __forceinline__ uint pkmax(uint a, uint b) {
    uint d; asm("v_pk_max_f16 %0,%1,%2" : "=v"(d) : "v"(a), "v"(b)); return d;
}
// bits 0,1 of a -> 0x0000FFFF / 0xFFFF0000 select words
__device__ __forceinline__ uint pmask2(uint a) {
    uint b = a & 3u;
    return ((b | (b << 15)) & 0x10001u) * 0xFFFFu;
}
__device__ __forceinline__ half8 pgen8h(uintx4 vv, uintx4 zz, uint mby,
                                        uint uip, uint wip) {
    union { uintx4 u; half8 h; } c;
    c.u.x = pkmax(pkmul(uip, vv.x), pkmul(wip, zz.x)) & pmask2(mby);
    c.u.y = pkmax(pkmul(uip, vv.y), pkmul(wip, zz.y)) & pmask2(mby >> 2);
    c.u.z = pkmax(pkmul(uip, vv.z), pkmul(wip, zz.z)) & pmask2(mby >> 4);
    c.u.w = pkmax(pkmul(uip, vv.w), pkmul(wip, zz.w)) & pmask2(mby >> 6);
    return c.h;
}

#define KEEP(x) asm volatile("" : "+v"(x))
// counted barrier: LDS-write visibility only; vmcnt stays counted at use sites
#define BARRIER() do { asm volatile("s_waitcnt lgkmcnt(0)" ::: "memory"); \
                       __builtin_amdgcn_s_barrier(); } while (0)

#define VZLOAD(S, j0) do {                                   \
    v##S##a = *(const uintx4*)(gvt + (j0) + sh8);            \
    v##S##b = *(const uintx4*)(gvt + (j0) + 32 + sh8);       \
    z##S##a = *(const uintx4*)(gzt + (j0) + sh8);            \
    z##S##b = *(const uintx4*)(gzt + (j0) + 32 + sh8);       \
} while (0)

__global__ __launch_bounds__(256, 2) void attn_kernel(
    const uchar* __restrict__ mb,      // [NN][512] bitmask
    const ushort* __restrict__ WhT,    // [H][FOUT][NN] fp16
    const float* __restrict__ el, const float* __restrict__ Kh,
    const ushort* __restrict__ vt, const ushort* __restrict__ zt,
    const ushort* __restrict__ hraw,
    void* __restrict__ outv)
{
    __shared__ __align__(16) ushort sB[2][2][64 * 72];  // [jhalf][dbuf] tiles

    const int t = threadIdx.x, lane = t & 63, wid = t >> 6;  // 4 waves
    const int rg = wid >> 1;       // row group (32 rows each)
    const int jh = wid & 1;        // j half (0: j<2048, 1: j>=2048)
    const int b = blockIdx.x;
    const int head = b & 7;                       // XCD swizzle
    const int ibase = (b >> 3) * 64;
    const int lm = lane & 15, lq = lane >> 4;
    const int sh8 = lq * 8;

    // per-lane row constants for rows lm and lm+16 of this wave's 32 rows
    const float kh = Kh[head];
    const int rowa = ibase + rg * 32 + lm;
    const float xa = el[(size_t)head * NN + rowa] + kh;
    const float xb = el[(size_t)head * NN + rowa + 16] + kh;
    const float Ma = fmaxf(xa, ALPHA * xa);
    const float Mb = fmaxf(xb, ALPHA * xb);
    const uint uipa = (uint)f2h(PSCALE * __expf(xa - Ma)) * 0x10001u;
    const uint wipa = (uint)f2h(PSCALE * __expf(ALPHA * xa - Ma)) * 0x10001u;
    const uint uipb = (uint)f2h(PSCALE * __expf(xb - Mb)) * 0x10001u;
    const uint wipb = (uint)f2h(PSCALE * __expf(ALPHA * xb - Mb)) * 0x10001u;

    // staging: the 128 threads of each j-half stage that half's tile.
    // st in [0,128): so = B row, sc = 64B col group (2 thr per row).
    const int jb = jh * 2048;
    const int st = rg * 64 + lane;
    const int so = st >> 1;
    const int sc = (st & 1) * 32;
    const ushort* gB = WhT + ((size_t)head * FOUT + so) * NN + jb + sc;
    const ushort* gvt = vt + (size_t)head * NN + jb;
    const ushort* gzt = zt + (size_t)head * NN + jb;
    const uchar* mra = mb + (size_t)rowa * 512 + (jb >> 3);
    const uchar* mrb = mra + 16 * 512;

    uintx4 rr0, rr1, rr2, rr3;
    uintx2 mka_s, mkb_s;

    auto gload = [&](int j0) {     // j0 local to this half, in [0,2048)
        rr0 = *(const uintx4*)(gB + j0);
        rr1 = *(const uintx4*)(gB + j0 + 8);
        rr2 = *(const uintx4*)(gB + j0 + 16);
        rr3 = *(const uintx4*)(gB + j0 + 24);
        mka_s = *(const uintx2*)(mra + (j0 >> 3));
        mkb_s = *(const uintx2*)(mrb + (j0 >> 3));
    };
    auto lwrite = [&](int buf) {
        ushort* d = &sB[jh][buf][so * 72 + sc];
        *(uintx4*)(d)      = rr0;
        *(uintx4*)(d + 8)  = rr1;
        *(uintx4*)(d + 16) = rr2;
        *(uintx4*)(d + 24) = rr3;
    };

    uintx4 v0a, v0b, z0a, z0b;
    uintx4 v1a, v1b, z1a, z1b;

    const half8 onesh = {(_Float16)1.f, (_Float16)1.f, (_Float16)1.f, (_Float16)1.f,
                         (_Float16)1.f, (_Float16)1.f, (_Float16)1.f, (_Float16)1.f};
    floatx4 Z = {0.f, 0.f, 0.f, 0.f};
    floatx4 C0 = Z, C1 = Z, C2 = Z, C3 = Z, Cd0 = Z;
    floatx4 C4 = Z, C5 = Z, C6 = Z, C7 = Z, Cd1 = Z;

    auto compute = [&](int buf, uintx2 mka, uintx2 mkb,
                       uintx4 vA, uintx4 vB, uintx4 zA, uintx4 zB) {
        uint m0a = mka.x >> sh8;
        uint m1a = mka.y >> sh8;
        uint m0b = mkb.x >> sh8;
        uint m1b = mkb.y >> sh8;
        half8 a0 = pgen8h(vA, zA, m0a, uipa, wipa);   // rows lm,    j 0..31
        half8 a1 = pgen8h(vB, zB, m1a, uipa, wipa);   // rows lm,    j 32..63
        half8 a2 = pgen8h(vA, zA, m0b, uipb, wipb);   // rows lm+16, j 0..31
        half8 a3 = pgen8h(vB, zB, m1b, uipb, wipb);   // rows lm+16, j 32..63
        const ushort* base = &sB[jh][buf][0];
        half8 b00 = *(const half8*)(base + (0  + lm) * 72 + sh8);
        half8 b10 = *(const half8*)(base + (16 + lm) * 72 + sh8);
        half8 b20 = *(const half8*)(base + (32 + lm) * 72 + sh8);
        half8 b30 = *(const half8*)(base + (48 + lm) * 72 + sh8);
        Cd0 = __builtin_amdgcn_mfma_f32_16x16x32_f16(a0, onesh, Cd0, 0, 0, 0);
        Cd1 = __builtin_amdgcn_mfma_f32_16x16x32_f16(a2, onesh, Cd1, 0, 0, 0);
        C0 = __builtin_amdgcn_mfma_f32_16x16x32_f16(a0, b00, C0, 0, 0, 0);
        C4 = __builtin_amdgcn_mfma_f32_16x16x32_f16(a2, b00, C4, 0, 0, 0);
        C1 = __builtin_amdgcn_mfma_f32_16x16x32_f16(a0, b10, C1, 0, 0, 0);
        C5 = __builtin_amdgcn_mfma_f32_16x16x32_f16(a2, b10, C5, 0, 0, 0);
        C2 = __builtin_amdgcn_mfma_f32_16x16x32_f16(a0, b20, C2, 0, 0, 0);
        C6 = __builtin_amdgcn_mfma_f32_16x16x32_f16(a2, b20, C6, 0, 0, 0);
        C3 = __builtin_amdgcn_mfma_f32_16x16x32_f16(a0, b30, C3, 0, 0, 0);
        C7 = __builtin_amdgcn_mfma_f32_16x16x32_f16(a2, b30, C7, 0, 0, 0);
        half8 b01 = *(const half8*)(base + (0  + lm) * 72 + 32 + sh8);
        half8 b11 = *(const half8*)(base + (16 + lm) * 72 + 32 + sh8);
        half8 b21 = *(const half8*)(base + (32 + lm) * 72 + 32 + sh8);
        half8 b31 = *(const half8*)(base + (48 + lm) * 72 + 32 + sh8);
        Cd0 = __builtin_amdgcn_mfma_f32_16x16x32_f16(a1, onesh, Cd0, 0, 0, 0);
        Cd1 = __builtin_amdgcn_mfma_f32_16x16x32_f16(a3, onesh, Cd1, 0, 0, 0);
        C0 = __builtin_amdgcn_mfma_f32_16x16x32_f16(a1, b01, C0, 0, 0, 0);
        C4 = __builtin_amdgcn_mfma_f32_16x16x32_f16(a3, b01, C4, 0, 0, 0);
        C1 = __builtin_amdgcn_mfma_f32_16x16x32_f16(a1, b11, C1, 0, 0, 0);
        C5 = __builtin_amdgcn_mfma_f32_16x16x32_f16(a3, b11, C5, 0, 0, 0);
        C2 = __builtin_amdgcn_mfma_f32_16x16x32_f16(a1, b21, C2, 0, 0, 0);
        C6 = __builtin_amdgcn_mfma_f32_16x16x32_f16(a3, b21, C6, 0, 0, 0);
        C3 = __builtin_amdgcn_mfma_f32_16x16x32_f16(a1, b31, C3, 0, 0, 0);
        C7 = __builtin_amdgcn_mfma_f32_16x16x32_f16(a3, b31, C7, 0, 0, 0);
    };

    // prologue: buf0 <- tile 0 of this half; rr <- tile 1; vz0 <- tile 0
    uintx2 mka0, mkb0, mka1, mkb1;
    gload(0);
    lwrite(0);
    mka0 = mka_s; mkb0 = mkb_s;
    gload(64);
    VZLOAD(0, 0);
    KEEP(rr0); KEEP(rr1); KEEP(rr2); KEEP(rr3);
    KEEP(v0a); KEEP(v0b); KEEP(z0a); KEEP(z0b);
    BARRIER();

    // main loop: 32 tiles per wave, 1 counted barrier per tile; prefetch
    // issued before compute and pinned live; loads cross the barrier.
    for (int it = 0; it < 32; it += 2) {
        // phase A: compute tile it (buf0, vz0)
        lwrite(1);                               // tile it+1 -> buf1
        mka1 = mka_s; mkb1 = mkb_s;
        gload(((it + 2) & 31) * 64);             // rr <- tile it+2
        VZLOAD(1, (it + 1) * 64);                // vz1 <- tile it+1
        compute(0, mka0, mkb0, v0a, v0b, z0a, z0b);
        KEEP(v1a); KEEP(v1b); KEEP(z1a); KEEP(z1b);
        KEEP(rr0); KEEP(rr1); KEEP(rr2); KEEP(rr3);
        BARRIER();
        // phase B: compute tile it+1 (buf1, vz1)
        lwrite(0);                               // tile it+2 -> buf0
        mka0 = mka_s; mkb0 = mkb_s;
        gload(((it + 3) & 31) * 64);             // rr <- tile it+3
        VZLOAD(0, ((it + 2) & 31) * 64);         // vz0 <- tile it+2
        compute(1, mka1, mkb1, v1a, v1b, z1a, z1b);
        KEEP(v0a); KEEP(v0b); KEEP(z0a); KEEP(z0b);
        KEEP(rr0); KEEP(rr1); KEEP(rr2); KEEP(rr3);
        BARRIER();
    }

    // merge j-halves: jh=1 waves publish partials via LDS, jh=0 accumulate.
    // lane stride 44 dwords (16B-aligned, odd/4 stride -> spread banks).
    float* mg = (float*)&sB[0][0][0];   // 22528 B needed <= 36864 B
    const int mi = (rg * 64 + lane) * 44;
    if (jh == 1) {
        float* p = &mg[mi];
        *(floatx4*)(p + 0)  = C0;  *(floatx4*)(p + 4)  = C1;
        *(floatx4*)(p + 8)  = C2;  *(floatx4*)(p + 12) = C3;
        *(floatx4*)(p + 16) = C4;  *(floatx4*)(p + 20) = C5;
        *(floatx4*)(p + 24) = C6;  *(floatx4*)(p + 28) = C7;
        *(floatx4*)(p + 32) = Cd0; *(floatx4*)(p + 36) = Cd1;
    }
    BARRIER();
    if (jh == 0) {
        const float* p = &mg[mi];
        C0 += *(const floatx4*)(p + 0);   C1 += *(const floatx4*)(p + 4);
        C2 += *(const floatx4*)(p + 8);   C3 += *(const floatx4*)(p + 12);
        C4 += *(const floatx4*)(p + 16);  C5 += *(const floatx4*)(p + 20);
        C6 += *(const floatx4*)(p + 24);  C7 += *(const floatx4*)(p + 28);
        Cd0 += *(const floatx4*)(p + 32); Cd1 += *(const floatx4*)(p + 36);

        // epilogue: normalize, elu, store (two row groups per lane)
        const int isbf = detect_bf16(hraw);
#pragma unroll
        for (int r = 0; r < 4; r++) {
            int ra = ibase + rg * 32 + lq * 4 + r;
            int rb = ra + 16;
            float inva = 1.f / Cd0[r];
            float invb = 1.f / Cd1[r];
            float x0 = C0[r] * inva; x0 = (x0 > 0.f) ? x0 : __expf(x0) - 1.f;
            float x1 = C1[r] * inva; x1 = (x1 > 0.f) ? x1 : __expf(x1) - 1.f;
            float x2 = C2[r] * inva; x2 = (x2 > 0.f) ? x2 : __expf(x2) - 1.f;
            float x3 = C3[r] * inva; x3 = (x3 > 0.f) ? x3 : __expf(x3) - 1.f;
            float y0 = C4[r] * invb; y0 = (y0 > 0.f) ? y0 : __expf(y0) - 1.f;
            float y1 = C5[r] * invb; y1 = (y1 > 0.f) ? y1 : __expf(y1) - 1.f;
            float y2 = C6[r] * invb; y2 = (y2 > 0.f) ? y2 : __expf(y2) - 1.f;
            float y3 = C7[r] * invb; y3 = (y3 > 0.f) ? y3 : __expf(y3) - 1.f;
            size_t basea = (size_t)ra * (NH * FOUT) + head * FOUT + lm;
            size_t baseb = (size_t)rb * (NH * FOUT) + head * FOUT + lm;
            if (isbf) {
                ushort* o = (ushort*)outv;
                o[basea + 0]  = f2bf(x0);
                o[basea + 16] = f2bf(x1);
                o[basea + 32] = f2bf(x2);
                o[basea + 48] = f2bf(x3);
                o[baseb + 0]  = f2bf(y0);
                o[baseb + 16] = f2bf(y1);
                o[baseb + 32] = f2bf(y2);
                o[baseb + 48] = f2bf(y3);
            } else {
                float* o = (float*)outv;
                o[basea + 0]  = x0;
                o[basea + 16] = x1;
                o[basea + 32] = x2;
                o[basea + 48] = x3;
                o[baseb + 0]  = y0;
                o[baseb + 16] = y1;
                o[baseb + 32] = y2;
                o[baseb + 48] = y3;
            }
        }
    }
}

extern "C" void kernel_launch(void* const* d_in, const int* in_sizes, int n_in,
                              void* d_out, int out_size, void* d_ws, size_t ws_size,
                              hipStream_t stream)
{
    const void* hraw = d_in[0];
    const int*  mask = (const int*)d_in[1];
    const void* Wraw = d_in[2];
    const void* bWr  = d_in[3];
    const void* alr  = d_in[4];
    const void* arr  = d_in[5];
    const void* bAr  = d_in[6];

    char* w = (char*)d_ws;
    ushort* bh   = (ushort*)w;                  w += (size_t)NN * FIN * 2;        // 4 MB
    ushort* WT   = (ushort*)w;                  w += (size_t)NH * FOUT * FIN * 2; // 512 KB
    ushort* WhT  = (ushort*)w;                  w += (size_t)NH * FOUT * NN * 2;  // 4 MB
    float*  el   = (float*)w;                   w += (size_t)NH * NN * 4;
    float*  er   = (float*)w;                   w += (size_t)NH * NN * 4;
    float*  Kh   = (float*)w;                   w += 64;
    ushort* vt   = (ushort*)w;                  w += (size_t)NH * NN * 4;  // fp16, slack kept
    ushort* zt   = (ushort*)w;                  w += (size_t)NH * NN * 4;
    uchar*  mb   = (uchar*)w;                   w += (size_t)NN * 512;            // 2 MB

    prep_kernel<<<PM_BLKS + CV_BLKS + TW_BLKS, 256, 0, stream>>>(
        mask, mb, hraw, bh, Wraw, WT);
    wh_kernel<<<dim3(NN / 64, NH), 256, 0, stream>>>(bh, WT, bWr, alr, arr, bAr,
                                                     (const ushort*)hraw, WhT, el, er);
    khv_kernel<<<64, 256, 0, stream>>>(er, Kh, vt, zt);
    attn_kernel<<<NN / 64 * NH, 256, 0, stream>>>(mb, WhT, el, Kh, vt, zt,
                                                  (const ushort*)hraw, d_out);
}